// Round 4
// baseline (711.101 us; speedup 1.0000x reference)
//
#include <hip/hip_runtime.h>
#include <hip/hip_bf16.h>
#include <stdint.h>

// ---------------------------------------------------------------------------
// TransformerSeqLayer: rel-pos sliding-window attention + post-LN + top-2 MoE
// All heavy matmuls on MFMA f16 16x16x32.
// Pre-gate path uses f16x2 split (hi + lo*2^-11, lo stored pre-scaled by 2^11)
// with dual accumulators => ~2^-22 relative error so top_idx matches fp32 ref.
// MoE path uses single f16 (0.14 absmax threshold is generous).
// Round 4: resubmit of round 3 (infra failure, no kernel evidence).
// global_load_lds (16B) async staging in gemm_k (diagnosis: VALUBusy 33% >
// MfmaUtil 25% = reg-staging bound); QKV tile 128x128 (MFMA density 2x).
// LDS layout: linear dest + pre-swizzled global source + swizzled ds_read.
// ---------------------------------------------------------------------------

typedef _Float16 f16;
typedef _Float16 f16x8 __attribute__((ext_vector_type(8)));
typedef _Float16 f16x4 __attribute__((ext_vector_type(4)));
typedef float    f32x4 __attribute__((ext_vector_type(4)));
typedef int      i32x4 __attribute__((ext_vector_type(4)));

#define MFMA16(a, b, c) __builtin_amdgcn_mfma_f32_16x16x32_f16((a), (b), (c), 0, 0, 0)
#define LO_SCALE 2048.0f
#define LO_INV   4.8828125e-4f   // 1/2048

__device__ __forceinline__ void split2(float x, f16* h, f16* l) {
  f16 hh = (f16)x;
  *h = hh;
  *l = (f16)((x - (float)hh) * LO_SCALE);
}

__device__ __forceinline__ f32x4 zero4() {
  f32x4 z; z[0] = 0.f; z[1] = 0.f; z[2] = 0.f; z[3] = 0.f; return z;
}

// async 16B global -> LDS (wave-uniform base + lane*16 dest; per-lane source)
__device__ __forceinline__ void gload_lds16(const void* g, void* l) {
  __builtin_amdgcn_global_load_lds((__attribute__((address_space(1))) void*)g,
                                   (__attribute__((address_space(3))) void*)l,
                                   16, 0, 0);
}

// ---------------------------------------------------------------------------
// Cast h_all = concat(h_cache, h) -> split planes [B*1024][1024]
// ---------------------------------------------------------------------------
__global__ void __launch_bounds__(256) cast_hall_k(const float* __restrict__ h,
                                                   const float* __restrict__ hc,
                                                   f16* __restrict__ hi,
                                                   f16* __restrict__ lo) {
  int c = blockIdx.x * 256 + threadIdx.x;   // chunk of 8 elems
  int e0 = c * 8;
  int row = e0 >> 10;
  int col = e0 & 1023;
  int b = row >> 10, pos = row & 1023;
  const float* src = (pos < 512) ? (hc + (size_t)((b << 9) + pos) * 1024 + col)
                                 : (h  + (size_t)((b << 9) + (pos - 512)) * 1024 + col);
  float4 v0 = ((const float4*)src)[0];
  float4 v1 = ((const float4*)src)[1];
  float xs[8] = {v0.x, v0.y, v0.z, v0.w, v1.x, v1.y, v1.z, v1.w};
  f16x8 vh, vl;
#pragma unroll
  for (int i = 0; i < 8; i++) { f16 a, bb; split2(xs[i], &a, &bb); vh[i] = a; vl[i] = bb; }
  *(f16x8*)&hi[e0] = vh;
  *(f16x8*)&lo[e0] = vl;
}

// ---------------------------------------------------------------------------
// Transpose + cast: in [R][C] fp32 -> out [C][R] f16 (split optional)
// ---------------------------------------------------------------------------
template <int SPLIT>
__global__ void __launch_bounds__(256) transpose_cast_k(const float* __restrict__ in,
                                                        f16* __restrict__ oh,
                                                        f16* __restrict__ ol,
                                                        int R, int C) {
  in += (size_t)blockIdx.z * R * C;
  oh += (size_t)blockIdx.z * R * C;
  if constexpr (SPLIT) ol += (size_t)blockIdx.z * R * C;
  __shared__ float tile[32][33];
  int c0 = blockIdx.x * 32, r0 = blockIdx.y * 32;
  int tr = threadIdx.x >> 3, tc = (threadIdx.x & 7) * 4;
  float4 v = *(const float4*)&in[(size_t)(r0 + tr) * C + c0 + tc];
  tile[tr][tc + 0] = v.x; tile[tr][tc + 1] = v.y; tile[tr][tc + 2] = v.z; tile[tr][tc + 3] = v.w;
  __syncthreads();
  int oc = tr;       // output row index within tile (input col)
  int orr = tc;      // output col group (input row)
  f16x4 vh, vl;
#pragma unroll
  for (int i = 0; i < 4; i++) {
    float x = tile[orr + i][oc];
    f16 a, bb; split2(x, &a, &bb);
    vh[i] = a; vl[i] = bb;
  }
  *(f16x4*)&oh[(size_t)(c0 + oc) * R + r0 + orr] = vh;
  if constexpr (SPLIT) *(f16x4*)&ol[(size_t)(c0 + oc) * R + r0 + orr] = vl;
}

// ---------------------------------------------------------------------------
// Generic NT GEMM: C[row][col] = sum_k A[row][k] * B[col][k]
// A: [rows][K] (hi/lo planes), B: [N][K] (transposed weights, hi/lo planes)
// SPLIT=1: dual accumulator f16x2 correction. Tile: BM x BN, BK=32.
// Wave layout: 2x2 waves, each (BM/2)x(BN/2). Staging via global_load_lds.
// ---------------------------------------------------------------------------
#define AM_ID 0
#define AM_GA 2
#define AM_PA 3
#define EP_QKV 0
#define EP_F32 2
#define EP_HE 3
#define EP_YE 4

template <int SPLIT, int BM, int BN, int AMAP, int EPI>
__global__ void __launch_bounds__(256) gemm_k(
    const f16* __restrict__ Ah, const f16* __restrict__ Al,
    const f16* __restrict__ Bh, const f16* __restrict__ Bl,
    void* __restrict__ o0, void* __restrict__ o1,
    const float* __restrict__ bias,
    int Kd, int strideA, int bExpStride,
    const int* __restrict__ list, const int* __restrict__ bases,
    const int* __restrict__ counts) {
  constexpr int PL = SPLIT ? 2 : 1;
  constexpr int MT = BM / 32;            // 16-row tiles per wave
  constexpr int NT = BN / 32;            // 16-col tiles per wave
  constexpr int AIT = BM / 64;           // A staging iters (256 thr, 16B units)
  constexpr int BIT = BN / 64;           // B staging iters
  const int e = blockIdx.z;
  int cnt = 0, base0 = 0;
  if constexpr (AMAP == AM_GA || AMAP == AM_PA) {
    cnt = counts[e]; base0 = bases[e];
    if ((int)blockIdx.y * BM >= cnt) return;
    Bh += (size_t)e * bExpStride;
  }
  __shared__ f16 sA[PL][BM * 32];
  __shared__ f16 sB[PL][BN * 32];
  const int n0 = blockIdx.x * BN, r0 = blockIdx.y * BM;
  const int tid = threadIdx.x, lane = tid & 63, wv = tid >> 6;
  const int wm = (wv >> 1) * (BM / 2), wn = (wv & 1) * (BN / 2);

  f32x4 accM[MT][NT], accC[MT][NT];
#pragma unroll
  for (int i = 0; i < MT; i++)
#pragma unroll
    for (int j = 0; j < NT; j++) { accM[i][j] = zero4(); accC[i][j] = zero4(); }

  // precompute A staging source rows/cols (constant over K loop)
  int aRow[AIT], aCu[AIT];
#pragma unroll
  for (int c = 0; c < AIT; c++) {
    int u = c * 256 + tid;
    int r = u >> 2, cu = u & 3;
    aCu[c] = ((cu ^ ((r >> 1) & 3)) << 3);
    int rr = r0 + r;
    int g;
    if constexpr (AMAP == AM_ID) g = rr;
    else if constexpr (AMAP == AM_GA) g = (rr < cnt) ? list[base0 + rr] : 0;
    else g = base0 + rr;
    aRow[c] = g;
  }
  int bRow[BIT], bCu[BIT];
#pragma unroll
  for (int c = 0; c < BIT; c++) {
    int u = c * 256 + tid;
    int r = u >> 2, cu = u & 3;
    bCu[c] = ((cu ^ ((r >> 1) & 3)) << 3);
    bRow[c] = n0 + r;
  }

  for (int k0 = 0; k0 < Kd; k0 += 32) {
    // async-stage A/B tiles: linear LDS dest (unit=u), pre-swizzled global col
#pragma unroll
    for (int c = 0; c < AIT; c++) {
      int u = c * 256 + tid;
      gload_lds16(&Ah[(size_t)aRow[c] * strideA + k0 + aCu[c]], &sA[0][u * 8]);
      if constexpr (SPLIT)
        gload_lds16(&Al[(size_t)aRow[c] * strideA + k0 + aCu[c]], &sA[1][u * 8]);
    }
#pragma unroll
    for (int c = 0; c < BIT; c++) {
      int u = c * 256 + tid;
      gload_lds16(&Bh[(size_t)bRow[c] * Kd + k0 + bCu[c]], &sB[0][u * 8]);
      if constexpr (SPLIT)
        gload_lds16(&Bl[(size_t)bRow[c] * Kd + k0 + bCu[c]], &sB[1][u * 8]);
    }
    __syncthreads();

    f16x8 ah[MT], al[MT];
#pragma unroll
    for (int mt = 0; mt < MT; mt++) {
      int r = wm + mt * 16 + (lane & 15);
      int cu = (lane >> 4) ^ ((r >> 1) & 3);
      ah[mt] = *(const f16x8*)&sA[0][(r * 4 + cu) * 8];
      if constexpr (SPLIT) al[mt] = *(const f16x8*)&sA[1][(r * 4 + cu) * 8];
    }
#pragma unroll
    for (int nt = 0; nt < NT; nt++) {
      int r = wn + nt * 16 + (lane & 15);
      int cu = (lane >> 4) ^ ((r >> 1) & 3);
      f16x8 bh = *(const f16x8*)&sB[0][(r * 4 + cu) * 8];
      f16x8 bl;
      if constexpr (SPLIT) bl = *(const f16x8*)&sB[1][(r * 4 + cu) * 8];
#pragma unroll
      for (int mt = 0; mt < MT; mt++) {
        accM[mt][nt] = MFMA16(ah[mt], bh, accM[mt][nt]);
        if constexpr (SPLIT) {
          accC[mt][nt] = MFMA16(ah[mt], bl, accC[mt][nt]);
          accC[mt][nt] = MFMA16(al[mt], bh, accC[mt][nt]);
        }
      }
    }
    __syncthreads();
  }

  // epilogue
#pragma unroll
  for (int mt = 0; mt < MT; mt++)
#pragma unroll
    for (int nt = 0; nt < NT; nt++)
#pragma unroll
      for (int rg = 0; rg < 4; rg++) {
        int row = r0 + wm + mt * 16 + ((lane >> 4) << 2) + rg;
        int col = n0 + wn + nt * 16 + (lane & 15);
        float v = accM[mt][nt][rg];
        if constexpr (SPLIT) v += accC[mt][nt][rg] * LO_INV;
        if constexpr (EPI == EP_QKV) {
          // rows are h_all rows [b*1024+pos]; cols: [0,1024)=Q, [1024,2048)=K,
          // [2048,3072)=V (stored transposed). Q only valid for pos>=512.
          f16* QH = (f16*)o0;
          f16* QL = QH + (1u << 21);
          f16* KH = QL + (1u << 21);
          f16* KL = KH + (1u << 22);
          f16* VTH = KL + (1u << 22);
          f16* VTL = VTH + (1u << 22);
          int b = row >> 10, pos = row & 1023;
          int seg = col >> 10, hd = (col >> 7) & 7, d = col & 127;
          f16 hh, ll; split2(v, &hh, &ll);
          if (seg == 0) {
            if (pos >= 512) {
              size_t ad = ((size_t)((((b << 3) + hd) << 9) + (pos - 512))) * 128 + d;
              QH[ad] = hh; QL[ad] = ll;
            }
          } else if (seg == 1) {
            size_t ad = ((size_t)((((b << 3) + hd) << 10) + pos)) * 128 + d;
            KH[ad] = hh; KL[ad] = ll;
          } else {
            size_t ad = ((size_t)((((b << 3) + hd) << 7) + d)) * 1024 + pos;
            VTH[ad] = hh; VTL[ad] = ll;
          }
        } else if constexpr (EPI == EP_F32) {
          ((float*)o0)[(size_t)row * 1024 + col] = v;
        } else if constexpr (EPI == EP_HE) {
          if (row < cnt) {
            float t = v + bias[(e << 11) + col];
            ((f16*)o0)[(size_t)(base0 + row) * 2048 + col] = (f16)fmaxf(t, 0.f);
          }
        } else if constexpr (EPI == EP_YE) {
          if (row < cnt)
            ((float*)o0)[(size_t)(base0 + row) * 1024 + col] = v + bias[(e << 10) + col];
        }
      }
}

// ---------------------------------------------------------------------------
// Windowed relative-position attention.
// One block = (b*8+head, 32 query rows). Window = 544 keys (32+512).
// S[32][548] in LDS: fp32 scores -> packed split-f16 probabilities in place.
// ---------------------------------------------------------------------------
__device__ __forceinline__ void unpack_p(const unsigned* sp, f16x8* hi, f16x8* lo) {
  i32x4 u0 = *(const i32x4*)sp;
  i32x4 u1 = *(const i32x4*)(sp + 4);
  i32x4 h, l;
  h[0] = (u0[0] & 0xffff) | (u0[1] << 16);
  h[1] = (u0[2] & 0xffff) | (u0[3] << 16);
  h[2] = (u1[0] & 0xffff) | (u1[1] << 16);
  h[3] = (u1[2] & 0xffff) | (u1[3] << 16);
  l[0] = (int)(((unsigned)u0[0] >> 16) | ((unsigned)u0[1] & 0xffff0000u));
  l[1] = (int)(((unsigned)u0[2] >> 16) | ((unsigned)u0[3] & 0xffff0000u));
  l[2] = (int)(((unsigned)u1[0] >> 16) | ((unsigned)u1[1] & 0xffff0000u));
  l[3] = (int)(((unsigned)u1[2] >> 16) | ((unsigned)u1[3] & 0xffff0000u));
  *hi = __builtin_bit_cast(f16x8, h);
  *lo = __builtin_bit_cast(f16x8, l);
}

__global__ void __launch_bounds__(256) attn_k(
    const f16* __restrict__ qh_, const f16* __restrict__ ql_,
    const f16* __restrict__ kh_, const f16* __restrict__ kl_,
    const f16* __restrict__ ph_, const f16* __restrict__ pl_,
    const f16* __restrict__ vh_, const f16* __restrict__ vl_,
    f16* __restrict__ oh_, f16* __restrict__ ol_) {
  __shared__ float S[32][548];
  const int bh = blockIdx.y;
  const int m0 = blockIdx.x * 32;
  const int tid = threadIdx.x, lane = tid & 63, wv = tid >> 6;
  const int lr = lane & 15, lgp = lane >> 4;

  // Q fragments (held in registers)
  f16x8 qh[2][4], ql[2][4];
  {
    const size_t qbase = ((size_t)bh * 512 + m0) * 128;
#pragma unroll
    for (int mt = 0; mt < 2; mt++)
#pragma unroll
      for (int kb = 0; kb < 4; kb++) {
        size_t off = qbase + (size_t)(mt * 16 + lr) * 128 + kb * 32 + lgp * 8;
        qh[mt][kb] = *(const f16x8*)&qh_[off];
        ql[mt][kb] = *(const f16x8*)&ql_[off];
      }
  }

  // phase 1: content scores  S[m][j] = q[m] . k[m0+j]
  {
    const size_t kbase = ((size_t)bh * 1024 + m0) * 128;
    int ntB = (wv < 2) ? wv * 9 : 18 + (wv - 2) * 8;
    int ntE = ntB + ((wv < 2) ? 9 : 8);
    for (int nt = ntB; nt < ntE; ++nt) {
      f16x8 kh[4], kl[4];
#pragma unroll
      for (int kb = 0; kb < 4; kb++) {
        size_t off = kbase + (size_t)(nt * 16 + lr) * 128 + kb * 32 + lgp * 8;
        kh[kb] = *(const f16x8*)&kh_[off];
        kl[kb] = *(const f16x8*)&kl_[off];
      }
      f32x4 aM[2], aC[2];
      aM[0] = zero4(); aM[1] = zero4(); aC[0] = zero4(); aC[1] = zero4();
#pragma unroll
      for (int kb = 0; kb < 4; kb++)
#pragma unroll
        for (int mt = 0; mt < 2; mt++) {
          aM[mt] = MFMA16(qh[mt][kb], kh[kb], aM[mt]);
          aC[mt] = MFMA16(qh[mt][kb], kl[kb], aC[mt]);
          aC[mt] = MFMA16(ql[mt][kb], kh[kb], aC[mt]);
        }
#pragma unroll
      for (int mt = 0; mt < 2; mt++)
#pragma unroll
        for (int rg = 0; rg < 4; rg++) {
          int m = mt * 16 + lgp * 4 + rg;
          S[m][nt * 16 + lr] = aM[mt][rg] + aC[mt][rg] * LO_INV;
        }
    }
  }
  __syncthreads();

  // phase 2: positional scores  S[m][m+l] += q[m] . pe[l]
  {
    for (int lt = wv * 8; lt < wv * 8 + 8; ++lt) {
      f16x8 eh[4], el[4];
#pragma unroll
      for (int kb = 0; kb < 4; kb++) {
        size_t off = (size_t)(lt * 16 + lr) * 128 + kb * 32 + lgp * 8;
        eh[kb] = *(const f16x8*)&ph_[off];
        el[kb] = *(const f16x8*)&pl_[off];
      }
      f32x4 aM[2], aC[2];
      aM[0] = zero4(); aM[1] = zero4(); aC[0] = zero4(); aC[1] = zero4();
#pragma unroll
      for (int kb = 0; kb < 4; kb++)
#pragma unroll
        for (int mt = 0; mt < 2; mt++) {
          aM[mt] = MFMA16(qh[mt][kb], eh[kb], aM[mt]);
          aC[mt] = MFMA16(qh[mt][kb], el[kb], aC[mt]);
          aC[mt] = MFMA16(ql[mt][kb], eh[kb], aC[mt]);
        }
#pragma unroll
      for (int mt = 0; mt < 2; mt++)
#pragma unroll
        for (int rg = 0; rg < 4; rg++) {
          int m = mt * 16 + lgp * 4 + rg;
          int lc = lt * 16 + lr;
          S[m][m + lc] += aM[mt][rg] + aC[mt][rg] * LO_INV;
        }
    }
  }
  __syncthreads();

  // phase 3: softmax over each row's valid window [m, m+512), write packed split P
  {
    const float scl = 0.08838834764831843f;  // 1/sqrt(128)
    for (int rr = 0; rr < 8; ++rr) {
      int m = wv * 8 + rr;
      float mx = -3.0e38f;
#pragma unroll
      for (int it = 0; it < 9; ++it) {
        int j = it * 64 + lane;
        if (j < 544 && j >= m && j < m + 512) mx = fmaxf(mx, S[m][j]);
      }
#pragma unroll
      for (int o = 32; o > 0; o >>= 1) mx = fmaxf(mx, __shfl_xor(mx, o));
      float pv[9]; float sm = 0.f;
#pragma unroll
      for (int it = 0; it < 9; ++it) {
        int j = it * 64 + lane;
        float p = 0.f;
        if (j < 544 && j >= m && j < m + 512) p = expf((S[m][j] - mx) * scl);
        pv[it] = p; sm += p;
      }
#pragma unroll
      for (int o = 32; o > 0; o >>= 1) sm += __shfl_xor(sm, o);
      float inv = 1.0f / sm;
#pragma unroll
      for (int it = 0; it < 9; ++it) {
        int j = it * 64 + lane;
        if (j < 544) {
          float pn = pv[it] * inv;
          f16 hh, ll; split2(pn, &hh, &ll);
          unsigned pk = (unsigned)__builtin_bit_cast(unsigned short, hh) |
                        ((unsigned)__builtin_bit_cast(unsigned short, ll) << 16);
          ((unsigned*)&S[m][0])[j] = pk;
        }
      }
    }
  }
  __syncthreads();

  // phase 4: O[m][d] = sum_j P[m][j] * V[m0+j][d]   (V stored transposed [d][pos])
  f32x4 accM[2][2], accC[2][2];
#pragma unroll
  for (int i = 0; i < 2; i++)
#pragma unroll
    for (int j = 0; j < 2; j++) { accM[i][j] = zero4(); accC[i][j] = zero4(); }
  for (int kb = 0; kb < 17; ++kb) {
    f16x8 pah[2], pal[2];
#pragma unroll
    for (int mt = 0; mt < 2; mt++) {
      const unsigned* sp = (const unsigned*)&S[mt * 16 + lr][0] + kb * 32 + lgp * 8;
      unpack_p(sp, &pah[mt], &pal[mt]);
    }
#pragma unroll
    for (int ntl = 0; ntl < 2; ++ntl) {
      int d = wv * 32 + ntl * 16 + lr;
      size_t off = ((size_t)bh * 128 + d) * 1024 + m0 + kb * 32 + lgp * 8;
      f16x8 vh = *(const f16x8*)&vh_[off];
      f16x8 vl = *(const f16x8*)&vl_[off];
#pragma unroll
      for (int mt = 0; mt < 2; mt++) {
        accM[mt][ntl] = MFMA16(pah[mt], vh, accM[mt][ntl]);
        accC[mt][ntl] = MFMA16(pah[mt], vl, accC[mt][ntl]);
        accC[mt][ntl] = MFMA16(pal[mt], vh, accC[mt][ntl]);
      }
    }
  }
  const int b = bh >> 3, hd = bh & 7;
#pragma unroll
  for (int mt = 0; mt < 2; mt++)
#pragma unroll
    for (int ntl = 0; ntl < 2; ntl++)
#pragma unroll
      for (int rg = 0; rg < 4; rg++) {
        int m = mt * 16 + lgp * 4 + rg;
        int d = wv * 32 + ntl * 16 + lr;
        float v = accM[mt][ntl][rg] + accC[mt][ntl][rg] * LO_INV;
        size_t ad = ((size_t)(b * 512 + m0 + m)) * 1024 + hd * 128 + d;
        f16 hh, ll; split2(v, &hh, &ll);
        oh_[ad] = hh; ol_[ad] = ll;
      }
}

// ---------------------------------------------------------------------------
// LayerNorm helpers / kernels (fp32)
// ---------------------------------------------------------------------------
__device__ __forceinline__ float blk_sum(float v, float* red) {
#pragma unroll
  for (int o = 32; o > 0; o >>= 1) v += __shfl_xor(v, o);
  int wv = threadIdx.x >> 6;
  if ((threadIdx.x & 63) == 0) red[wv] = v;
  __syncthreads();
  float r = red[0] + red[1] + red[2] + red[3];
  __syncthreads();
  return r;
}

__global__ void __launch_bounds__(256) ln1_k(const float* __restrict__ h,
                                             const float* __restrict__ ap,
                                             const float* __restrict__ g,
                                             const float* __restrict__ bb,
                                             float* __restrict__ h1,
                                             f16* __restrict__ h1h) {
  int row = blockIdx.x;
  __shared__ float red[4];
  float4 hv = ((const float4*)(h + (size_t)row * 1024))[threadIdx.x];
  float4 av = ((const float4*)(ap + (size_t)row * 1024))[threadIdx.x];
  float4 x; x.x = hv.x + av.x; x.y = hv.y + av.y; x.z = hv.z + av.z; x.w = hv.w + av.w;
  float s = x.x + x.y + x.z + x.w;
  s = blk_sum(s, red);
  float mean = s * (1.0f / 1024.0f);
  float4 d; d.x = x.x - mean; d.y = x.y - mean; d.z = x.z - mean; d.w = x.w - mean;
  float s2 = d.x * d.x + d.y * d.y + d.z * d.z + d.w * d.w;
  s2 = blk_sum(s2, red);
  float var = s2 * (1.0f / 1024.0f);
  float inv = 1.0f / sqrtf(var + 1e-5f);
  float4 gv = ((const float4*)g)[threadIdx.x];
  float4 bv = ((const float4*)bb)[threadIdx.x];
  float4 y; y.x = d.x * inv * gv.x + bv.x; y.y = d.y * inv * gv.y + bv.y;
  y.z = d.z * inv * gv.z + bv.z; y.w = d.w * inv * gv.w + bv.w;
  ((float4*)(h1 + (size_t)row * 1024))[threadIdx.x] = y;
  f16x4 yh; yh[0] = (f16)y.x; yh[1] = (f16)y.y; yh[2] = (f16)y.z; yh[3] = (f16)y.w;
  *(f16x4*)&h1h[(size_t)row * 1024 + threadIdx.x * 4] = yh;
}

// ---------------------------------------------------------------------------
// Gate: logits = h1 @ gate_W + gate_b, top-2, softmax, counts
// ---------------------------------------------------------------------------
__global__ void __launch_bounds__(256) gate_k(const float* __restrict__ h1,
                                              const float* __restrict__ gW,
                                              const float* __restrict__ gb,
                                              float* __restrict__ outIdx,
                                              float* __restrict__ sc,
                                              int* __restrict__ te,
                                              int* __restrict__ ctrl) {
  int t = blockIdx.x * 4 + (threadIdx.x >> 6);
  int lane = threadIdx.x & 63;
  float a0 = 0, a1 = 0, a2 = 0, a3 = 0, a4 = 0, a5 = 0, a6 = 0, a7 = 0;
  for (int i = lane; i < 1024; i += 64) {
    float x = h1[(size_t)t * 1024 + i];
    const float4* w = (const float4*)&gW[i * 8];
    float4 w0 = w[0], w1 = w[1];
    a0 += x * w0.x; a1 += x * w0.y; a2 += x * w0.z; a3 += x * w0.w;
    a4 += x * w1.x; a5 += x * w1.y; a6 += x * w1.z; a7 += x * w1.w;
  }
  float av[8] = {a0, a1, a2, a3, a4, a5, a6, a7};
#pragma unroll
  for (int e = 0; e < 8; e++)
#pragma unroll
    for (int o = 32; o > 0; o >>= 1) av[e] += __shfl_xor(av[e], o);
  if (lane == 0) {
#pragma unroll
    for (int e = 0; e < 8; e++) av[e] += gb[e];
    int i0 = 0; float v0 = av[0];
#pragma unroll
    for (int e = 1; e < 8; e++) if (av[e] > v0) { v0 = av[e]; i0 = e; }
    int i1 = -1; float v1 = -3.0e38f;
#pragma unroll
    for (int e = 0; e < 8; e++) if (e != i0 && av[e] > v1) { v1 = av[e]; i1 = e; }
    float ex = expf(v1 - v0);
    float den = 1.0f + ex;
    outIdx[t * 2] = (float)i0; outIdx[t * 2 + 1] = (float)i1;
    sc[t * 2] = 1.0f / den; sc[t * 2 + 1] = ex / den;
    te[t * 2] = i0; te[t * 2 + 1] = i1;
    atomicAdd(&ctrl[i0], 1); atomicAdd(&ctrl[i1], 1);
  }
}

__global__ void scan_k(int* ctrl) {
  if (threadIdx.x == 0 && blockIdx.x == 0) {
    int s = 0;
    for (int e = 0; e < 8; e++) { ctrl[8 + e] = s; s += ctrl[e]; }
  }
}

__global__ void __launch_bounds__(256) scatter_k(const int* __restrict__ te,
                                                 int* ctrl,
                                                 int* __restrict__ list,
                                                 int* __restrict__ ppos) {
  int t = blockIdx.x * 256 + threadIdx.x;
  if (t >= 2048) return;
#pragma unroll
  for (int s = 0; s < 2; s++) {
    int e = te[t * 2 + s];
    int pos = atomicAdd(&ctrl[16 + e], 1);
    int pr = ctrl[8 + e] + pos;
    list[pr] = t;
    ppos[t * 2 + s] = pr;
  }
}

// ---------------------------------------------------------------------------
// Combine MoE outputs + final LayerNorm
// ---------------------------------------------------------------------------
__global__ void __launch_bounds__(256) comb_ln2_k(const float* __restrict__ h1,
                                                  const float* __restrict__ ye,
                                                  const float* __restrict__ sc,
                                                  const int* __restrict__ ppos,
                                                  const float* __restrict__ g,
                                                  const float* __restrict__ bb,
                                                  float* __restrict__ out) {
  int row = blockIdx.x;
  __shared__ float red[4];
  int p0 = ppos[row * 2], p1 = ppos[row * 2 + 1];
  float s0 = sc[row * 2], s1 = sc[row * 2 + 1];
  float4 a = ((const float4*)(h1 + (size_t)row * 1024))[threadIdx.x];
  float4 y0 = ((const float4*)(ye + (size_t)p0 * 1024))[threadIdx.x];
  float4 y1 = ((const float4*)(ye + (size_t)p1 * 1024))[threadIdx.x];
  float4 x;
  x.x = a.x + s0 * y0.x + s1 * y1.x; x.y = a.y + s0 * y0.y + s1 * y1.y;
  x.z = a.z + s0 * y0.z + s1 * y1.z; x.w = a.w + s0 * y0.w + s1 * y1.w;
  float s = x.x + x.y + x.z + x.w;
  s = blk_sum(s, red);
  float mean = s * (1.0f / 1024.0f);
  float4 d; d.x = x.x - mean; d.y = x.y - mean; d.z = x.z - mean; d.w = x.w - mean;
  float s2 = d.x * d.x + d.y * d.y + d.z * d.z + d.w * d.w;
  s2 = blk_sum(s2, red);
  float var = s2 * (1.0f / 1024.0f);
  float inv = 1.0f / sqrtf(var + 1e-5f);
  float4 gv = ((const float4*)g)[threadIdx.x];
  float4 bv = ((const float4*)bb)[threadIdx.x];
  float4 y; y.x = d.x * inv * gv.x + bv.x; y.y = d.y * inv * gv.y + bv.y;
  y.z = d.z * inv * gv.z + bv.z; y.w = d.w * inv * gv.w + bv.w;
  ((float4*)(out + (size_t)row * 1024))[threadIdx.x] = y;
}

// ---------------------------------------------------------------------------
// Host launch
// ---------------------------------------------------------------------------
extern "C" void kernel_launch(void* const* d_in, const int* in_sizes, int n_in,
                              void* d_out, int out_size, void* d_ws, size_t ws_size,
                              hipStream_t stream) {
  const float* h   = (const float*)d_in[0];
  const float* hc  = (const float*)d_in[1];
  const float* pe  = (const float*)d_in[2];
  const float* Wq  = (const float*)d_in[3];
  const float* Wk  = (const float*)d_in[4];
  const float* Wv  = (const float*)d_in[5];
  const float* Wo  = (const float*)d_in[6];
  const float* g1  = (const float*)d_in[7];
  const float* b1n = (const float*)d_in[8];
  const float* gW  = (const float*)d_in[9];
  const float* gb  = (const float*)d_in[10];
  const float* W1  = (const float*)d_in[11];
  const float* b1e = (const float*)d_in[12];
  const float* W2  = (const float*)d_in[13];
  const float* b2e = (const float*)d_in[14];
  const float* g2  = (const float*)d_in[15];
  const float* b2n = (const float*)d_in[16];
  float* out = (float*)d_out;
  float* outIdx = out + 2097152;

  char* w = (char*)d_ws;
  size_t off = 0;
  auto alloc = [&](size_t bytes) -> char* {
    char* p = w + off;
    off += (bytes + 255) & ~(size_t)255;
    return p;
  };
  int*   ctrl    = (int*)alloc(128);
  f16*   hallH   = (f16*)alloc(4096ull * 1024 * 2);
  f16*   hallL   = (f16*)alloc(4096ull * 1024 * 2);
  f16*   WqkvtH  = (f16*)alloc(3072ull * 1024 * 2);
  f16*   WqkvtL  = (f16*)alloc(3072ull * 1024 * 2);
  f16*   WotH    = (f16*)alloc(1024ull * 1024 * 2);
  f16*   WotL    = (f16*)alloc(1024ull * 1024 * 2);
  f16*   peH     = (f16*)alloc(512ull * 128 * 2);
  f16*   peL     = (f16*)alloc(512ull * 128 * 2);
  // contiguous qkv block; offsets hard-coded in EP_QKV epilogue
  f16*   qkv     = (f16*)alloc(20971520ull * 2);
  f16*   qH  = qkv;
  f16*   qL  = qH + (1u << 21);
  f16*   kH  = qL + (1u << 21);
  f16*   kL  = kH + (1u << 22);
  f16*   vtH = kL + (1u << 22);
  f16*   vtL = vtH + (1u << 22);
  f16*   attH  = (f16*)alloc(2097152ull * 2);
  f16*   attL  = (f16*)alloc(2097152ull * 2);
  float* aproj = (float*)alloc(2097152ull * 4);
  float* h1    = (float*)alloc(2097152ull * 4);
  f16*   h1h   = (f16*)alloc(2097152ull * 2);
  f16*   W1t   = (f16*)alloc(16777216ull * 2);
  f16*   W2t   = (f16*)alloc(16777216ull * 2);
  f16*   he    = (f16*)alloc(4224ull * 2048 * 2);
  float* ye    = (float*)alloc(4224ull * 1024 * 4);
  float* scb   = (float*)alloc(2048ull * 2 * 4);
  int*   te    = (int*)alloc(2048ull * 2 * 4);
  int*   ppos  = (int*)alloc(2048ull * 2 * 4);
  int*   list  = (int*)alloc(4096ull * 4);
  (void)in_sizes; (void)n_in; (void)out_size; (void)ws_size;

  hipMemsetAsync(ctrl, 0, 128, stream);

  // casts / transposes
  cast_hall_k<<<2048, 256, 0, stream>>>(h, hc, hallH, hallL);
  transpose_cast_k<1><<<dim3(32, 32, 1), 256, 0, stream>>>(Wq, WqkvtH, WqkvtL, 1024, 1024);
  transpose_cast_k<1><<<dim3(32, 32, 1), 256, 0, stream>>>(Wk, WqkvtH + 1048576, WqkvtL + 1048576, 1024, 1024);
  transpose_cast_k<1><<<dim3(32, 32, 1), 256, 0, stream>>>(Wv, WqkvtH + 2097152, WqkvtL + 2097152, 1024, 1024);
  transpose_cast_k<1><<<dim3(32, 32, 1), 256, 0, stream>>>(Wo, WotH, WotL, 1024, 1024);
  transpose_cast_k<1><<<dim3(16, 4, 1), 256, 0, stream>>>(pe, peH, peL, 128, 512);
  transpose_cast_k<0><<<dim3(64, 32, 8), 256, 0, stream>>>(W1, W1t, nullptr, 1024, 2048);
  transpose_cast_k<0><<<dim3(32, 64, 8), 256, 0, stream>>>(W2, W2t, nullptr, 2048, 1024);

  // merged QKV projection over h_all (N=3072): 768 blocks, 128x128 split tile
  gemm_k<1, 128, 128, AM_ID, EP_QKV><<<dim3(24, 32, 1), 256, 0, stream>>>(
      hallH, hallL, WqkvtH, WqkvtL, qkv, nullptr, nullptr, 1024, 1024, 0,
      nullptr, nullptr, nullptr);

  // attention
  attn_k<<<dim3(16, 32, 1), 256, 0, stream>>>(qH, qL, kH, kL, peH, peL, vtH, vtL, attH, attL);

  // output projection + LN1 (64x64 tile: 512 blocks)
  gemm_k<1, 64, 64, AM_ID, EP_F32><<<dim3(16, 32, 1), 256, 0, stream>>>(
      attH, attL, WotH, WotL, aproj, nullptr, nullptr, 1024, 1024, 0,
      nullptr, nullptr, nullptr);
  ln1_k<<<2048, 256, 0, stream>>>(h, aproj, g1, b1n, h1, h1h);

  // gate + routing
  gate_k<<<512, 256, 0, stream>>>(h1, gW, gb, outIdx, scb, te, ctrl);
  scan_k<<<1, 64, 0, stream>>>(ctrl);
  scatter_k<<<8, 256, 0, stream>>>(te, ctrl, list, ppos);

  // expert FFNs (64-row tiles)
  gemm_k<0, 64, 128, AM_GA, EP_HE><<<dim3(16, 32, 8), 256, 0, stream>>>(
      h1h, nullptr, W1t, nullptr, he, nullptr, b1e, 1024, 1024, 2048 * 1024,
      list, ctrl + 8, ctrl);
  gemm_k<0, 64, 128, AM_PA, EP_YE><<<dim3(8, 32, 8), 256, 0, stream>>>(
      he, nullptr, W2t, nullptr, ye, nullptr, b2e, 2048, 2048, 1024 * 2048,
      nullptr, ctrl + 8, ctrl);

  // combine + LN2
  comb_ln2_k<<<2048, 256, 0, stream>>>(h1, ye, scb, ppos, g2, b2n, out);
}

// Round 5
// 669.185 us; speedup vs baseline: 1.0626x; 1.0626x over previous
//
#include <hip/hip_runtime.h>
#include <hip/hip_bf16.h>
#include <stdint.h>

// ---------------------------------------------------------------------------
// TransformerSeqLayer: rel-pos sliding-window attention + post-LN + top-2 MoE
// All heavy matmuls on MFMA f16 16x16x32.
// Pre-gate path uses f16x2 split (hi + lo*2^-11, lo stored pre-scaled by 2^11)
// with dual accumulators => ~2^-22 relative error so top_idx matches fp32 ref.
// MoE path uses single f16 (0.14 absmax threshold is generous).
// Round 5: keep global_load_lds async staging; revert QKV tile to 128x64.
// R4 lesson: 128x128 split tile = 128 AGPR + 140 VGPR = 268 regs -> 1 wave/SIMD
// (Occupancy 10.4%), MfmaUtil 17%. 128x64 split = ~148 regs -> 3 waves/SIMD.
// ---------------------------------------------------------------------------

typedef _Float16 f16;
typedef _Float16 f16x8 __attribute__((ext_vector_type(8)));
typedef _Float16 f16x4 __attribute__((ext_vector_type(4)));
typedef float    f32x4 __attribute__((ext_vector_type(4)));
typedef int      i32x4 __attribute__((ext_vector_type(4)));

#define MFMA16(a, b, c) __builtin_amdgcn_mfma_f32_16x16x32_f16((a), (b), (c), 0, 0, 0)
#define LO_SCALE 2048.0f
#define LO_INV   4.8828125e-4f   // 1/2048

__device__ __forceinline__ void split2(float x, f16* h, f16* l) {
  f16 hh = (f16)x;
  *h = hh;
  *l = (f16)((x - (float)hh) * LO_SCALE);
}

__device__ __forceinline__ f32x4 zero4() {
  f32x4 z; z[0] = 0.f; z[1] = 0.f; z[2] = 0.f; z[3] = 0.f; return z;
}

// async 16B global -> LDS (wave-uniform base + lane*16 dest; per-lane source)
__device__ __forceinline__ void gload_lds16(const void* g, void* l) {
  __builtin_amdgcn_global_load_lds((__attribute__((address_space(1))) void*)g,
                                   (__attribute__((address_space(3))) void*)l,
                                   16, 0, 0);
}

// ---------------------------------------------------------------------------
// Cast h_all = concat(h_cache, h) -> split planes [B*1024][1024]
// ---------------------------------------------------------------------------
__global__ void __launch_bounds__(256) cast_hall_k(const float* __restrict__ h,
                                                   const float* __restrict__ hc,
                                                   f16* __restrict__ hi,
                                                   f16* __restrict__ lo) {
  int c = blockIdx.x * 256 + threadIdx.x;   // chunk of 8 elems
  int e0 = c * 8;
  int row = e0 >> 10;
  int col = e0 & 1023;
  int b = row >> 10, pos = row & 1023;
  const float* src = (pos < 512) ? (hc + (size_t)((b << 9) + pos) * 1024 + col)
                                 : (h  + (size_t)((b << 9) + (pos - 512)) * 1024 + col);
  float4 v0 = ((const float4*)src)[0];
  float4 v1 = ((const float4*)src)[1];
  float xs[8] = {v0.x, v0.y, v0.z, v0.w, v1.x, v1.y, v1.z, v1.w};
  f16x8 vh, vl;
#pragma unroll
  for (int i = 0; i < 8; i++) { f16 a, bb; split2(xs[i], &a, &bb); vh[i] = a; vl[i] = bb; }
  *(f16x8*)&hi[e0] = vh;
  *(f16x8*)&lo[e0] = vl;
}

// ---------------------------------------------------------------------------
// Transpose + cast: in [R][C] fp32 -> out [C][R] f16 (split optional)
// ---------------------------------------------------------------------------
template <int SPLIT>
__global__ void __launch_bounds__(256) transpose_cast_k(const float* __restrict__ in,
                                                        f16* __restrict__ oh,
                                                        f16* __restrict__ ol,
                                                        int R, int C) {
  in += (size_t)blockIdx.z * R * C;
  oh += (size_t)blockIdx.z * R * C;
  if constexpr (SPLIT) ol += (size_t)blockIdx.z * R * C;
  __shared__ float tile[32][33];
  int c0 = blockIdx.x * 32, r0 = blockIdx.y * 32;
  int tr = threadIdx.x >> 3, tc = (threadIdx.x & 7) * 4;
  float4 v = *(const float4*)&in[(size_t)(r0 + tr) * C + c0 + tc];
  tile[tr][tc + 0] = v.x; tile[tr][tc + 1] = v.y; tile[tr][tc + 2] = v.z; tile[tr][tc + 3] = v.w;
  __syncthreads();
  int oc = tr;       // output row index within tile (input col)
  int orr = tc;      // output col group (input row)
  f16x4 vh, vl;
#pragma unroll
  for (int i = 0; i < 4; i++) {
    float x = tile[orr + i][oc];
    f16 a, bb; split2(x, &a, &bb);
    vh[i] = a; vl[i] = bb;
  }
  *(f16x4*)&oh[(size_t)(c0 + oc) * R + r0 + orr] = vh;
  if constexpr (SPLIT) *(f16x4*)&ol[(size_t)(c0 + oc) * R + r0 + orr] = vl;
}

// ---------------------------------------------------------------------------
// Generic NT GEMM: C[row][col] = sum_k A[row][k] * B[col][k]
// A: [rows][K] (hi/lo planes), B: [N][K] (transposed weights, hi/lo planes)
// SPLIT=1: dual accumulator f16x2 correction. Tile: BM x BN, BK=32.
// Wave layout: 2x2 waves, each (BM/2)x(BN/2). Staging via global_load_lds.
// ---------------------------------------------------------------------------
#define AM_ID 0
#define AM_GA 2
#define AM_PA 3
#define EP_QKV 0
#define EP_F32 2
#define EP_HE 3
#define EP_YE 4

template <int SPLIT, int BM, int BN, int AMAP, int EPI>
__global__ void __launch_bounds__(256) gemm_k(
    const f16* __restrict__ Ah, const f16* __restrict__ Al,
    const f16* __restrict__ Bh, const f16* __restrict__ Bl,
    void* __restrict__ o0, void* __restrict__ o1,
    const float* __restrict__ bias,
    int Kd, int strideA, int bExpStride,
    const int* __restrict__ list, const int* __restrict__ bases,
    const int* __restrict__ counts) {
  constexpr int PL = SPLIT ? 2 : 1;
  constexpr int MT = BM / 32;            // 16-row tiles per wave
  constexpr int NT = BN / 32;            // 16-col tiles per wave
  constexpr int AIT = BM / 64;           // A staging iters (256 thr, 16B units)
  constexpr int BIT = BN / 64;           // B staging iters
  const int e = blockIdx.z;
  int cnt = 0, base0 = 0;
  if constexpr (AMAP == AM_GA || AMAP == AM_PA) {
    cnt = counts[e]; base0 = bases[e];
    if ((int)blockIdx.y * BM >= cnt) return;
    Bh += (size_t)e * bExpStride;
  }
  __shared__ f16 sA[PL][BM * 32];
  __shared__ f16 sB[PL][BN * 32];
  const int n0 = blockIdx.x * BN, r0 = blockIdx.y * BM;
  const int tid = threadIdx.x, lane = tid & 63, wv = tid >> 6;
  const int wm = (wv >> 1) * (BM / 2), wn = (wv & 1) * (BN / 2);

  f32x4 accM[MT][NT], accC[MT][NT];
#pragma unroll
  for (int i = 0; i < MT; i++)
#pragma unroll
    for (int j = 0; j < NT; j++) { accM[i][j] = zero4(); accC[i][j] = zero4(); }

  // precompute A staging source rows/cols (constant over K loop)
  int aRow[AIT], aCu[AIT];
#pragma unroll
  for (int c = 0; c < AIT; c++) {
    int u = c * 256 + tid;
    int r = u >> 2, cu = u & 3;
    aCu[c] = ((cu ^ ((r >> 1) & 3)) << 3);
    int rr = r0 + r;
    int g;
    if constexpr (AMAP == AM_ID) g = rr;
    else if constexpr (AMAP == AM_GA) g = (rr < cnt) ? list[base0 + rr] : 0;
    else g = base0 + rr;
    aRow[c] = g;
  }
  int bRow[BIT], bCu[BIT];
#pragma unroll
  for (int c = 0; c < BIT; c++) {
    int u = c * 256 + tid;
    int r = u >> 2, cu = u & 3;
    bCu[c] = ((cu ^ ((r >> 1) & 3)) << 3);
    bRow[c] = n0 + r;
  }

  for (int k0 = 0; k0 < Kd; k0 += 32) {
    // async-stage A/B tiles: linear LDS dest (unit=u), pre-swizzled global col
#pragma unroll
    for (int c = 0; c < AIT; c++) {
      int u = c * 256 + tid;
      gload_lds16(&Ah[(size_t)aRow[c] * strideA + k0 + aCu[c]], &sA[0][u * 8]);
      if constexpr (SPLIT)
        gload_lds16(&Al[(size_t)aRow[c] * strideA + k0 + aCu[c]], &sA[1][u * 8]);
    }
#pragma unroll
    for (int c = 0; c < BIT; c++) {
      int u = c * 256 + tid;
      gload_lds16(&Bh[(size_t)bRow[c] * Kd + k0 + bCu[c]], &sB[0][u * 8]);
      if constexpr (SPLIT)
        gload_lds16(&Bl[(size_t)bRow[c] * Kd + k0 + bCu[c]], &sB[1][u * 8]);
    }
    __syncthreads();

    f16x8 ah[MT], al[MT];
#pragma unroll
    for (int mt = 0; mt < MT; mt++) {
      int r = wm + mt * 16 + (lane & 15);
      int cu = (lane >> 4) ^ ((r >> 1) & 3);
      ah[mt] = *(const f16x8*)&sA[0][(r * 4 + cu) * 8];
      if constexpr (SPLIT) al[mt] = *(const f16x8*)&sA[1][(r * 4 + cu) * 8];
    }
#pragma unroll
    for (int nt = 0; nt < NT; nt++) {
      int r = wn + nt * 16 + (lane & 15);
      int cu = (lane >> 4) ^ ((r >> 1) & 3);
      f16x8 bh = *(const f16x8*)&sB[0][(r * 4 + cu) * 8];
      f16x8 bl;
      if constexpr (SPLIT) bl = *(const f16x8*)&sB[1][(r * 4 + cu) * 8];
#pragma unroll
      for (int mt = 0; mt < MT; mt++) {
        accM[mt][nt] = MFMA16(ah[mt], bh, accM[mt][nt]);
        if constexpr (SPLIT) {
          accC[mt][nt] = MFMA16(ah[mt], bl, accC[mt][nt]);
          accC[mt][nt] = MFMA16(al[mt], bh, accC[mt][nt]);
        }
      }
    }
    __syncthreads();
  }

  // epilogue
#pragma unroll
  for (int mt = 0; mt < MT; mt++)
#pragma unroll
    for (int nt = 0; nt < NT; nt++)
#pragma unroll
      for (int rg = 0; rg < 4; rg++) {
        int row = r0 + wm + mt * 16 + ((lane >> 4) << 2) + rg;
        int col = n0 + wn + nt * 16 + (lane & 15);
        float v = accM[mt][nt][rg];
        if constexpr (SPLIT) v += accC[mt][nt][rg] * LO_INV;
        if constexpr (EPI == EP_QKV) {
          // rows are h_all rows [b*1024+pos]; cols: [0,1024)=Q, [1024,2048)=K,
          // [2048,3072)=V (stored transposed). Q only valid for pos>=512.
          f16* QH = (f16*)o0;
          f16* QL = QH + (1u << 21);
          f16* KH = QL + (1u << 21);
          f16* KL = KH + (1u << 22);
          f16* VTH = KL + (1u << 22);
          f16* VTL = VTH + (1u << 22);
          int b = row >> 10, pos = row & 1023;
          int seg = col >> 10, hd = (col >> 7) & 7, d = col & 127;
          f16 hh, ll; split2(v, &hh, &ll);
          if (seg == 0) {
            if (pos >= 512) {
              size_t ad = ((size_t)((((b << 3) + hd) << 9) + (pos - 512))) * 128 + d;
              QH[ad] = hh; QL[ad] = ll;
            }
          } else if (seg == 1) {
            size_t ad = ((size_t)((((b << 3) + hd) << 10) + pos)) * 128 + d;
            KH[ad] = hh; KL[ad] = ll;
          } else {
            size_t ad = ((size_t)((((b << 3) + hd) << 7) + d)) * 1024 + pos;
            VTH[ad] = hh; VTL[ad] = ll;
          }
        } else if constexpr (EPI == EP_F32) {
          ((float*)o0)[(size_t)row * 1024 + col] = v;
        } else if constexpr (EPI == EP_HE) {
          if (row < cnt) {
            float t = v + bias[(e << 11) + col];
            ((f16*)o0)[(size_t)(base0 + row) * 2048 + col] = (f16)fmaxf(t, 0.f);
          }
        } else if constexpr (EPI == EP_YE) {
          if (row < cnt)
            ((float*)o0)[(size_t)(base0 + row) * 1024 + col] = v + bias[(e << 10) + col];
        }
      }
}

// ---------------------------------------------------------------------------
// Windowed relative-position attention.
// One block = (b*8+head, 32 query rows). Window = 544 keys (32+512).
// S[32][548] in LDS: fp32 scores -> packed split-f16 probabilities in place.
// ---------------------------------------------------------------------------
__device__ __forceinline__ void unpack_p(const unsigned* sp, f16x8* hi, f16x8* lo) {
  i32x4 u0 = *(const i32x4*)sp;
  i32x4 u1 = *(const i32x4*)(sp + 4);
  i32x4 h, l;
  h[0] = (u0[0] & 0xffff) | (u0[1] << 16);
  h[1] = (u0[2] & 0xffff) | (u0[3] << 16);
  h[2] = (u1[0] & 0xffff) | (u1[1] << 16);
  h[3] = (u1[2] & 0xffff) | (u1[3] << 16);
  l[0] = (int)(((unsigned)u0[0] >> 16) | ((unsigned)u0[1] & 0xffff0000u));
  l[1] = (int)(((unsigned)u0[2] >> 16) | ((unsigned)u0[3] & 0xffff0000u));
  l[2] = (int)(((unsigned)u1[0] >> 16) | ((unsigned)u1[1] & 0xffff0000u));
  l[3] = (int)(((unsigned)u1[2] >> 16) | ((unsigned)u1[3] & 0xffff0000u));
  *hi = __builtin_bit_cast(f16x8, h);
  *lo = __builtin_bit_cast(f16x8, l);
}

__global__ void __launch_bounds__(256) attn_k(
    const f16* __restrict__ qh_, const f16* __restrict__ ql_,
    const f16* __restrict__ kh_, const f16* __restrict__ kl_,
    const f16* __restrict__ ph_, const f16* __restrict__ pl_,
    const f16* __restrict__ vh_, const f16* __restrict__ vl_,
    f16* __restrict__ oh_, f16* __restrict__ ol_) {
  __shared__ float S[32][548];
  const int bh = blockIdx.y;
  const int m0 = blockIdx.x * 32;
  const int tid = threadIdx.x, lane = tid & 63, wv = tid >> 6;
  const int lr = lane & 15, lgp = lane >> 4;

  // Q fragments (held in registers)
  f16x8 qh[2][4], ql[2][4];
  {
    const size_t qbase = ((size_t)bh * 512 + m0) * 128;
#pragma unroll
    for (int mt = 0; mt < 2; mt++)
#pragma unroll
      for (int kb = 0; kb < 4; kb++) {
        size_t off = qbase + (size_t)(mt * 16 + lr) * 128 + kb * 32 + lgp * 8;
        qh[mt][kb] = *(const f16x8*)&qh_[off];
        ql[mt][kb] = *(const f16x8*)&ql_[off];
      }
  }

  // phase 1: content scores  S[m][j] = q[m] . k[m0+j]
  {
    const size_t kbase = ((size_t)bh * 1024 + m0) * 128;
    int ntB = (wv < 2) ? wv * 9 : 18 + (wv - 2) * 8;
    int ntE = ntB + ((wv < 2) ? 9 : 8);
    for (int nt = ntB; nt < ntE; ++nt) {
      f16x8 kh[4], kl[4];
#pragma unroll
      for (int kb = 0; kb < 4; kb++) {
        size_t off = kbase + (size_t)(nt * 16 + lr) * 128 + kb * 32 + lgp * 8;
        kh[kb] = *(const f16x8*)&kh_[off];
        kl[kb] = *(const f16x8*)&kl_[off];
      }
      f32x4 aM[2], aC[2];
      aM[0] = zero4(); aM[1] = zero4(); aC[0] = zero4(); aC[1] = zero4();
#pragma unroll
      for (int kb = 0; kb < 4; kb++)
#pragma unroll
        for (int mt = 0; mt < 2; mt++) {
          aM[mt] = MFMA16(qh[mt][kb], kh[kb], aM[mt]);
          aC[mt] = MFMA16(qh[mt][kb], kl[kb], aC[mt]);
          aC[mt] = MFMA16(ql[mt][kb], kh[kb], aC[mt]);
        }
#pragma unroll
      for (int mt = 0; mt < 2; mt++)
#pragma unroll
        for (int rg = 0; rg < 4; rg++) {
          int m = mt * 16 + lgp * 4 + rg;
          S[m][nt * 16 + lr] = aM[mt][rg] + aC[mt][rg] * LO_INV;
        }
    }
  }
  __syncthreads();

  // phase 2: positional scores  S[m][m+l] += q[m] . pe[l]
  {
    for (int lt = wv * 8; lt < wv * 8 + 8; ++lt) {
      f16x8 eh[4], el[4];
#pragma unroll
      for (int kb = 0; kb < 4; kb++) {
        size_t off = (size_t)(lt * 16 + lr) * 128 + kb * 32 + lgp * 8;
        eh[kb] = *(const f16x8*)&ph_[off];
        el[kb] = *(const f16x8*)&pl_[off];
      }
      f32x4 aM[2], aC[2];
      aM[0] = zero4(); aM[1] = zero4(); aC[0] = zero4(); aC[1] = zero4();
#pragma unroll
      for (int kb = 0; kb < 4; kb++)
#pragma unroll
        for (int mt = 0; mt < 2; mt++) {
          aM[mt] = MFMA16(qh[mt][kb], eh[kb], aM[mt]);
          aC[mt] = MFMA16(qh[mt][kb], el[kb], aC[mt]);
          aC[mt] = MFMA16(ql[mt][kb], eh[kb], aC[mt]);
        }
#pragma unroll
      for (int mt = 0; mt < 2; mt++)
#pragma unroll
        for (int rg = 0; rg < 4; rg++) {
          int m = mt * 16 + lgp * 4 + rg;
          int lc = lt * 16 + lr;
          S[m][m + lc] += aM[mt][rg] + aC[mt][rg] * LO_INV;
        }
    }
  }
  __syncthreads();

  // phase 3: softmax over each row's valid window [m, m+512), write packed split P
  {
    const float scl = 0.08838834764831843f;  // 1/sqrt(128)
    for (int rr = 0; rr < 8; ++rr) {
      int m = wv * 8 + rr;
      float mx = -3.0e38f;
#pragma unroll
      for (int it = 0; it < 9; ++it) {
        int j = it * 64 + lane;
        if (j < 544 && j >= m && j < m + 512) mx = fmaxf(mx, S[m][j]);
      }
#pragma unroll
      for (int o = 32; o > 0; o >>= 1) mx = fmaxf(mx, __shfl_xor(mx, o));
      float pv[9]; float sm = 0.f;
#pragma unroll
      for (int it = 0; it < 9; ++it) {
        int j = it * 64 + lane;
        float p = 0.f;
        if (j < 544 && j >= m && j < m + 512) p = expf((S[m][j] - mx) * scl);
        pv[it] = p; sm += p;
      }
#pragma unroll
      for (int o = 32; o > 0; o >>= 1) sm += __shfl_xor(sm, o);
      float inv = 1.0f / sm;
#pragma unroll
      for (int it = 0; it < 9; ++it) {
        int j = it * 64 + lane;
        if (j < 544) {
          float pn = pv[it] * inv;
          f16 hh, ll; split2(pn, &hh, &ll);
          unsigned pk = (unsigned)__builtin_bit_cast(unsigned short, hh) |
                        ((unsigned)__builtin_bit_cast(unsigned short, ll) << 16);
          ((unsigned*)&S[m][0])[j] = pk;
        }
      }
    }
  }
  __syncthreads();

  // phase 4: O[m][d] = sum_j P[m][j] * V[m0+j][d]   (V stored transposed [d][pos])
  f32x4 accM[2][2], accC[2][2];
#pragma unroll
  for (int i = 0; i < 2; i++)
#pragma unroll
    for (int j = 0; j < 2; j++) { accM[i][j] = zero4(); accC[i][j] = zero4(); }
  for (int kb = 0; kb < 17; ++kb) {
    f16x8 pah[2], pal[2];
#pragma unroll
    for (int mt = 0; mt < 2; mt++) {
      const unsigned* sp = (const unsigned*)&S[mt * 16 + lr][0] + kb * 32 + lgp * 8;
      unpack_p(sp, &pah[mt], &pal[mt]);
    }
#pragma unroll
    for (int ntl = 0; ntl < 2; ++ntl) {
      int d = wv * 32 + ntl * 16 + lr;
      size_t off = ((size_t)bh * 128 + d) * 1024 + m0 + kb * 32 + lgp * 8;
      f16x8 vh = *(const f16x8*)&vh_[off];
      f16x8 vl = *(const f16x8*)&vl_[off];
#pragma unroll
      for (int mt = 0; mt < 2; mt++) {
        accM[mt][ntl] = MFMA16(pah[mt], vh, accM[mt][ntl]);
        accC[mt][ntl] = MFMA16(pah[mt], vl, accC[mt][ntl]);
        accC[mt][ntl] = MFMA16(pal[mt], vh, accC[mt][ntl]);
      }
    }
  }
  const int b = bh >> 3, hd = bh & 7;
#pragma unroll
  for (int mt = 0; mt < 2; mt++)
#pragma unroll
    for (int ntl = 0; ntl < 2; ntl++)
#pragma unroll
      for (int rg = 0; rg < 4; rg++) {
        int m = mt * 16 + lgp * 4 + rg;
        int d = wv * 32 + ntl * 16 + lr;
        float v = accM[mt][ntl][rg] + accC[mt][ntl][rg] * LO_INV;
        size_t ad = ((size_t)(b * 512 + m0 + m)) * 1024 + hd * 128 + d;
        f16 hh, ll; split2(v, &hh, &ll);
        oh_[ad] = hh; ol_[ad] = ll;
      }
}

// ---------------------------------------------------------------------------
// LayerNorm helpers / kernels (fp32)
// ---------------------------------------------------------------------------
__device__ __forceinline__ float blk_sum(float v, float* red) {
#pragma unroll
  for (int o = 32; o > 0; o >>= 1) v += __shfl_xor(v, o);
  int wv = threadIdx.x >> 6;
  if ((threadIdx.x & 63) == 0) red[wv] = v;
  __syncthreads();
  float r = red[0] + red[1] + red[2] + red[3];
  __syncthreads();
  return r;
}

__global__ void __launch_bounds__(256) ln1_k(const float* __restrict__ h,
                                             const float* __restrict__ ap,
                                             const float* __restrict__ g,
                                             const float* __restrict__ bb,
                                             float* __restrict__ h1,
                                             f16* __restrict__ h1h) {
  int row = blockIdx.x;
  __shared__ float red[4];
  float4 hv = ((const float4*)(h + (size_t)row * 1024))[threadIdx.x];
  float4 av = ((const float4*)(ap + (size_t)row * 1024))[threadIdx.x];
  float4 x; x.x = hv.x + av.x; x.y = hv.y + av.y; x.z = hv.z + av.z; x.w = hv.w + av.w;
  float s = x.x + x.y + x.z + x.w;
  s = blk_sum(s, red);
  float mean = s * (1.0f / 1024.0f);
  float4 d; d.x = x.x - mean; d.y = x.y - mean; d.z = x.z - mean; d.w = x.w - mean;
  float s2 = d.x * d.x + d.y * d.y + d.z * d.z + d.w * d.w;
  s2 = blk_sum(s2, red);
  float var = s2 * (1.0f / 1024.0f);
  float inv = 1.0f / sqrtf(var + 1e-5f);
  float4 gv = ((const float4*)g)[threadIdx.x];
  float4 bv = ((const float4*)bb)[threadIdx.x];
  float4 y; y.x = d.x * inv * gv.x + bv.x; y.y = d.y * inv * gv.y + bv.y;
  y.z = d.z * inv * gv.z + bv.z; y.w = d.w * inv * gv.w + bv.w;
  ((float4*)(h1 + (size_t)row * 1024))[threadIdx.x] = y;
  f16x4 yh; yh[0] = (f16)y.x; yh[1] = (f16)y.y; yh[2] = (f16)y.z; yh[3] = (f16)y.w;
  *(f16x4*)&h1h[(size_t)row * 1024 + threadIdx.x * 4] = yh;
}

// ---------------------------------------------------------------------------
// Gate: logits = h1 @ gate_W + gate_b, top-2, softmax, counts
// ---------------------------------------------------------------------------
__global__ void __launch_bounds__(256) gate_k(const float* __restrict__ h1,
                                              const float* __restrict__ gW,
                                              const float* __restrict__ gb,
                                              float* __restrict__ outIdx,
                                              float* __restrict__ sc,
                                              int* __restrict__ te,
                                              int* __restrict__ ctrl) {
  int t = blockIdx.x * 4 + (threadIdx.x >> 6);
  int lane = threadIdx.x & 63;
  float a0 = 0, a1 = 0, a2 = 0, a3 = 0, a4 = 0, a5 = 0, a6 = 0, a7 = 0;
  for (int i = lane; i < 1024; i += 64) {
    float x = h1[(size_t)t * 1024 + i];
    const float4* w = (const float4*)&gW[i * 8];
    float4 w0 = w[0], w1 = w[1];
    a0 += x * w0.x; a1 += x * w0.y; a2 += x * w0.z; a3 += x * w0.w;
    a4 += x * w1.x; a5 += x * w1.y; a6 += x * w1.z; a7 += x * w1.w;
  }
  float av[8] = {a0, a1, a2, a3, a4, a5, a6, a7};
#pragma unroll
  for (int e = 0; e < 8; e++)
#pragma unroll
    for (int o = 32; o > 0; o >>= 1) av[e] += __shfl_xor(av[e], o);
  if (lane == 0) {
#pragma unroll
    for (int e = 0; e < 8; e++) av[e] += gb[e];
    int i0 = 0; float v0 = av[0];
#pragma unroll
    for (int e = 1; e < 8; e++) if (av[e] > v0) { v0 = av[e]; i0 = e; }
    int i1 = -1; float v1 = -3.0e38f;
#pragma unroll
    for (int e = 0; e < 8; e++) if (e != i0 && av[e] > v1) { v1 = av[e]; i1 = e; }
    float ex = expf(v1 - v0);
    float den = 1.0f + ex;
    outIdx[t * 2] = (float)i0; outIdx[t * 2 + 1] = (float)i1;
    sc[t * 2] = 1.0f / den; sc[t * 2 + 1] = ex / den;
    te[t * 2] = i0; te[t * 2 + 1] = i1;
    atomicAdd(&ctrl[i0], 1); atomicAdd(&ctrl[i1], 1);
  }
}

__global__ void scan_k(int* ctrl) {
  if (threadIdx.x == 0 && blockIdx.x == 0) {
    int s = 0;
    for (int e = 0; e < 8; e++) { ctrl[8 + e] = s; s += ctrl[e]; }
  }
}

__global__ void __launch_bounds__(256) scatter_k(const int* __restrict__ te,
                                                 int* ctrl,
                                                 int* __restrict__ list,
                                                 int* __restrict__ ppos) {
  int t = blockIdx.x * 256 + threadIdx.x;
  if (t >= 2048) return;
#pragma unroll
  for (int s = 0; s < 2; s++) {
    int e = te[t * 2 + s];
    int pos = atomicAdd(&ctrl[16 + e], 1);
    int pr = ctrl[8 + e] + pos;
    list[pr] = t;
    ppos[t * 2 + s] = pr;
  }
}

// ---------------------------------------------------------------------------
// Combine MoE outputs + final LayerNorm
// ---------------------------------------------------------------------------
__global__ void __launch_bounds__(256) comb_ln2_k(const float* __restrict__ h1,
                                                  const float* __restrict__ ye,
                                                  const float* __restrict__ sc,
                                                  const int* __restrict__ ppos,
                                                  const float* __restrict__ g,
                                                  const float* __restrict__ bb,
                                                  float* __restrict__ out) {
  int row = blockIdx.x;
  __shared__ float red[4];
  int p0 = ppos[row * 2], p1 = ppos[row * 2 + 1];
  float s0 = sc[row * 2], s1 = sc[row * 2 + 1];
  float4 a = ((const float4*)(h1 + (size_t)row * 1024))[threadIdx.x];
  float4 y0 = ((const float4*)(ye + (size_t)p0 * 1024))[threadIdx.x];
  float4 y1 = ((const float4*)(ye + (size_t)p1 * 1024))[threadIdx.x];
  float4 x;
  x.x = a.x + s0 * y0.x + s1 * y1.x; x.y = a.y + s0 * y0.y + s1 * y1.y;
  x.z = a.z + s0 * y0.z + s1 * y1.z; x.w = a.w + s0 * y0.w + s1 * y1.w;
  float s = x.x + x.y + x.z + x.w;
  s = blk_sum(s, red);
  float mean = s * (1.0f / 1024.0f);
  float4 d; d.x = x.x - mean; d.y = x.y - mean; d.z = x.z - mean; d.w = x.w - mean;
  float s2 = d.x * d.x + d.y * d.y + d.z * d.z + d.w * d.w;
  s2 = blk_sum(s2, red);
  float var = s2 * (1.0f / 1024.0f);
  float inv = 1.0f / sqrtf(var + 1e-5f);
  float4 gv = ((const float4*)g)[threadIdx.x];
  float4 bv = ((const float4*)bb)[threadIdx.x];
  float4 y; y.x = d.x * inv * gv.x + bv.x; y.y = d.y * inv * gv.y + bv.y;
  y.z = d.z * inv * gv.z + bv.z; y.w = d.w * inv * gv.w + bv.w;
  ((float4*)(out + (size_t)row * 1024))[threadIdx.x] = y;
}

// ---------------------------------------------------------------------------
// Host launch
// ---------------------------------------------------------------------------
extern "C" void kernel_launch(void* const* d_in, const int* in_sizes, int n_in,
                              void* d_out, int out_size, void* d_ws, size_t ws_size,
                              hipStream_t stream) {
  const float* h   = (const float*)d_in[0];
  const float* hc  = (const float*)d_in[1];
  const float* pe  = (const float*)d_in[2];
  const float* Wq  = (const float*)d_in[3];
  const float* Wk  = (const float*)d_in[4];
  const float* Wv  = (const float*)d_in[5];
  const float* Wo  = (const float*)d_in[6];
  const float* g1  = (const float*)d_in[7];
  const float* b1n = (const float*)d_in[8];
  const float* gW  = (const float*)d_in[9];
  const float* gb  = (const float*)d_in[10];
  const float* W1  = (const float*)d_in[11];
  const float* b1e = (const float*)d_in[12];
  const float* W2  = (const float*)d_in[13];
  const float* b2e = (const float*)d_in[14];
  const float* g2  = (const float*)d_in[15];
  const float* b2n = (const float*)d_in[16];
  float* out = (float*)d_out;
  float* outIdx = out + 2097152;

  char* w = (char*)d_ws;
  size_t off = 0;
  auto alloc = [&](size_t bytes) -> char* {
    char* p = w + off;
    off += (bytes + 255) & ~(size_t)255;
    return p;
  };
  int*   ctrl    = (int*)alloc(128);
  f16*   hallH   = (f16*)alloc(4096ull * 1024 * 2);
  f16*   hallL   = (f16*)alloc(4096ull * 1024 * 2);
  f16*   WqkvtH  = (f16*)alloc(3072ull * 1024 * 2);
  f16*   WqkvtL  = (f16*)alloc(3072ull * 1024 * 2);
  f16*   WotH    = (f16*)alloc(1024ull * 1024 * 2);
  f16*   WotL    = (f16*)alloc(1024ull * 1024 * 2);
  f16*   peH     = (f16*)alloc(512ull * 128 * 2);
  f16*   peL     = (f16*)alloc(512ull * 128 * 2);
  // contiguous qkv block; offsets hard-coded in EP_QKV epilogue
  f16*   qkv     = (f16*)alloc(20971520ull * 2);
  f16*   qH  = qkv;
  f16*   qL  = qH + (1u << 21);
  f16*   kH  = qL + (1u << 21);
  f16*   kL  = kH + (1u << 22);
  f16*   vtH = kL + (1u << 22);
  f16*   vtL = vtH + (1u << 22);
  f16*   attH  = (f16*)alloc(2097152ull * 2);
  f16*   attL  = (f16*)alloc(2097152ull * 2);
  float* aproj = (float*)alloc(2097152ull * 4);
  float* h1    = (float*)alloc(2097152ull * 4);
  f16*   h1h   = (f16*)alloc(2097152ull * 2);
  f16*   W1t   = (f16*)alloc(16777216ull * 2);
  f16*   W2t   = (f16*)alloc(16777216ull * 2);
  f16*   he    = (f16*)alloc(4224ull * 2048 * 2);
  float* ye    = (float*)alloc(4224ull * 1024 * 4);
  float* scb   = (float*)alloc(2048ull * 2 * 4);
  int*   te    = (int*)alloc(2048ull * 2 * 4);
  int*   ppos  = (int*)alloc(2048ull * 2 * 4);
  int*   list  = (int*)alloc(4096ull * 4);
  (void)in_sizes; (void)n_in; (void)out_size; (void)ws_size;

  hipMemsetAsync(ctrl, 0, 128, stream);

  // casts / transposes
  cast_hall_k<<<2048, 256, 0, stream>>>(h, hc, hallH, hallL);
  transpose_cast_k<1><<<dim3(32, 32, 1), 256, 0, stream>>>(Wq, WqkvtH, WqkvtL, 1024, 1024);
  transpose_cast_k<1><<<dim3(32, 32, 1), 256, 0, stream>>>(Wk, WqkvtH + 1048576, WqkvtL + 1048576, 1024, 1024);
  transpose_cast_k<1><<<dim3(32, 32, 1), 256, 0, stream>>>(Wv, WqkvtH + 2097152, WqkvtL + 2097152, 1024, 1024);
  transpose_cast_k<1><<<dim3(32, 32, 1), 256, 0, stream>>>(Wo, WotH, WotL, 1024, 1024);
  transpose_cast_k<1><<<dim3(16, 4, 1), 256, 0, stream>>>(pe, peH, peL, 128, 512);
  transpose_cast_k<0><<<dim3(64, 32, 8), 256, 0, stream>>>(W1, W1t, nullptr, 1024, 2048);
  transpose_cast_k<0><<<dim3(32, 64, 8), 256, 0, stream>>>(W2, W2t, nullptr, 2048, 1024);

  // merged QKV projection over h_all (N=3072): 1536 blocks, 128x64 split tile
  gemm_k<1, 128, 64, AM_ID, EP_QKV><<<dim3(48, 32, 1), 256, 0, stream>>>(
      hallH, hallL, WqkvtH, WqkvtL, qkv, nullptr, nullptr, 1024, 1024, 0,
      nullptr, nullptr, nullptr);

  // attention
  attn_k<<<dim3(16, 32, 1), 256, 0, stream>>>(qH, qL, kH, kL, peH, peL, vtH, vtL, attH, attL);

  // output projection + LN1 (64x64 tile: 512 blocks)
  gemm_k<1, 64, 64, AM_ID, EP_F32><<<dim3(16, 32, 1), 256, 0, stream>>>(
      attH, attL, WotH, WotL, aproj, nullptr, nullptr, 1024, 1024, 0,
      nullptr, nullptr, nullptr);
  ln1_k<<<2048, 256, 0, stream>>>(h, aproj, g1, b1n, h1, h1h);

  // gate + routing
  gate_k<<<512, 256, 0, stream>>>(h1, gW, gb, outIdx, scb, te, ctrl);
  scan_k<<<1, 64, 0, stream>>>(ctrl);
  scatter_k<<<8, 256, 0, stream>>>(te, ctrl, list, ppos);

  // expert FFNs (64-row tiles)
  gemm_k<0, 64, 128, AM_GA, EP_HE><<<dim3(16, 32, 8), 256, 0, stream>>>(
      h1h, nullptr, W1t, nullptr, he, nullptr, b1e, 1024, 1024, 2048 * 1024,
      list, ctrl + 8, ctrl);
  gemm_k<0, 64, 128, AM_PA, EP_YE><<<dim3(8, 32, 8), 256, 0, stream>>>(
      he, nullptr, W2t, nullptr, ye, nullptr, b2e, 2048, 2048, 1024 * 2048,
      nullptr, ctrl + 8, ctrl);

  // combine + LN2
  comb_ln2_k<<<2048, 256, 0, stream>>>(h1, ye, scb, ppos, g2, b2n, out);
}

// Round 6
// 665.018 us; speedup vs baseline: 1.0693x; 1.0063x over previous
//
#include <hip/hip_runtime.h>
#include <hip/hip_bf16.h>
#include <stdint.h>

// ---------------------------------------------------------------------------
// TransformerSeqLayer: rel-pos sliding-window attention + post-LN + top-2 MoE
// All heavy matmuls on MFMA f16 16x16x32.
// Pre-gate path uses f16x2 split (hi + lo*2^-11, lo stored pre-scaled by 2^11)
// with dual accumulators => ~2^-22 relative error so top_idx matches fp32 ref.
// Round 6: B operand bypasses LDS entirely. Weights pre-packed fragment-major
// (1KB blob per 16n x 32k tile); waves load B global->VGPR (L2-hot, HBM 12%
// idle). R5 diagnosis: LDS port bound (12 ds_read + 24KB stage vs 120clk MFMA
// per K-step) -- async staging changed nothing because traffic, not mechanism,
// was the limit. LDS now stages A only (16KB/step QKV).
// ---------------------------------------------------------------------------

typedef _Float16 f16;
typedef _Float16 f16x8 __attribute__((ext_vector_type(8)));
typedef _Float16 f16x4 __attribute__((ext_vector_type(4)));
typedef float    f32x4 __attribute__((ext_vector_type(4)));
typedef int      i32x4 __attribute__((ext_vector_type(4)));

#define MFMA16(a, b, c) __builtin_amdgcn_mfma_f32_16x16x32_f16((a), (b), (c), 0, 0, 0)
#define LO_SCALE 2048.0f
#define LO_INV   4.8828125e-4f   // 1/2048

__device__ __forceinline__ void split2(float x, f16* h, f16* l) {
  f16 hh = (f16)x;
  *h = hh;
  *l = (f16)((x - (float)hh) * LO_SCALE);
}

__device__ __forceinline__ f32x4 zero4() {
  f32x4 z; z[0] = 0.f; z[1] = 0.f; z[2] = 0.f; z[3] = 0.f; return z;
}

// async 16B global -> LDS (wave-uniform base + lane*16 dest; per-lane source)
__device__ __forceinline__ void gload_lds16(const void* g, void* l) {
  __builtin_amdgcn_global_load_lds((__attribute__((address_space(1))) void*)g,
                                   (__attribute__((address_space(3))) void*)l,
                                   16, 0, 0);
}

// ---------------------------------------------------------------------------
// Cast h_all = concat(h_cache, h) -> split planes [B*1024][1024]
// ---------------------------------------------------------------------------
__global__ void __launch_bounds__(256) cast_hall_k(const float* __restrict__ h,
                                                   const float* __restrict__ hc,
                                                   f16* __restrict__ hi,
                                                   f16* __restrict__ lo) {
  int c = blockIdx.x * 256 + threadIdx.x;   // chunk of 8 elems
  int e0 = c * 8;
  int row = e0 >> 10;
  int col = e0 & 1023;
  int b = row >> 10, pos = row & 1023;
  const float* src = (pos < 512) ? (hc + (size_t)((b << 9) + pos) * 1024 + col)
                                 : (h  + (size_t)((b << 9) + (pos - 512)) * 1024 + col);
  float4 v0 = ((const float4*)src)[0];
  float4 v1 = ((const float4*)src)[1];
  float xs[8] = {v0.x, v0.y, v0.z, v0.w, v1.x, v1.y, v1.z, v1.w};
  f16x8 vh, vl;
#pragma unroll
  for (int i = 0; i < 8; i++) { f16 a, bb; split2(xs[i], &a, &bb); vh[i] = a; vl[i] = bb; }
  *(f16x8*)&hi[e0] = vh;
  *(f16x8*)&lo[e0] = vl;
}

// ---------------------------------------------------------------------------
// Weight prep: fp32 W[k][n] -> MFMA fragment-major f16 planes.
// Blob layout: B'[gnt][kt][lane][8], gnt = n/16, kt = k/32, lane = lgp*16+lr;
// element (lane,j) = W[k0 + lgp*8 + j][n0 + lr].  One wave load = 1KB coalesced.
// Block: 32k x 32n tile (2 n-tiles). SPLIT=1 emits hi+lo planes.
// ---------------------------------------------------------------------------
template <int SPLIT>
__global__ void __launch_bounds__(256) wprep_k(const float* __restrict__ in,
                                               f16* __restrict__ oh,
                                               f16* __restrict__ ol,
                                               int K, int N) {
  in += (size_t)blockIdx.z * K * N;
  oh += (size_t)blockIdx.z * K * N;
  if constexpr (SPLIT) ol += (size_t)blockIdx.z * K * N;
  __shared__ float tile[32][33];
  const int n0 = blockIdx.x * 32, k0 = blockIdx.y * 32;
  {
    int r = threadIdx.x >> 3, c4 = (threadIdx.x & 7) * 4;
    float4 v = *(const float4*)&in[(size_t)(k0 + r) * N + n0 + c4];
    tile[r][c4 + 0] = v.x; tile[r][c4 + 1] = v.y;
    tile[r][c4 + 2] = v.z; tile[r][c4 + 3] = v.w;
  }
  __syncthreads();
  int t = threadIdx.x;
  if constexpr (!SPLIT) { if (t >= 128) return; }
  int half = SPLIT ? (t >> 7) : 0;
  int r = t & 127;
  int nt = r >> 6, lane = r & 63;
  int lr = lane & 15, lgp = lane >> 4;
  f16x8 v;
#pragma unroll
  for (int j = 0; j < 8; j++) {
    float x = tile[lgp * 8 + j][nt * 16 + lr];
    f16 hh, ll; split2(x, &hh, &ll);
    v[j] = half ? ll : hh;
  }
  size_t blob = (((size_t)(n0 >> 4) + nt) * (K >> 5) + (k0 >> 5)) * 512 + lane * 8;
  f16* dst = half ? ol : oh;
  *(f16x8*)&dst[blob] = v;
}

// ---------------------------------------------------------------------------
// Transpose + cast (kept for pe only): in [R][C] fp32 -> out [C][R] f16 split
// ---------------------------------------------------------------------------
template <int SPLIT>
__global__ void __launch_bounds__(256) transpose_cast_k(const float* __restrict__ in,
                                                        f16* __restrict__ oh,
                                                        f16* __restrict__ ol,
                                                        int R, int C) {
  in += (size_t)blockIdx.z * R * C;
  oh += (size_t)blockIdx.z * R * C;
  if constexpr (SPLIT) ol += (size_t)blockIdx.z * R * C;
  __shared__ float tile[32][33];
  int c0 = blockIdx.x * 32, r0 = blockIdx.y * 32;
  int tr = threadIdx.x >> 3, tc = (threadIdx.x & 7) * 4;
  float4 v = *(const float4*)&in[(size_t)(r0 + tr) * C + c0 + tc];
  tile[tr][tc + 0] = v.x; tile[tr][tc + 1] = v.y; tile[tr][tc + 2] = v.z; tile[tr][tc + 3] = v.w;
  __syncthreads();
  int oc = tr;
  int orr = tc;
  f16x4 vh, vl;
#pragma unroll
  for (int i = 0; i < 4; i++) {
    float x = tile[orr + i][oc];
    f16 a, bb; split2(x, &a, &bb);
    vh[i] = a; vl[i] = bb;
  }
  *(f16x4*)&oh[(size_t)(c0 + oc) * R + r0 + orr] = vh;
  if constexpr (SPLIT) *(f16x4*)&ol[(size_t)(c0 + oc) * R + r0 + orr] = vl;
}

// ---------------------------------------------------------------------------
// Generic GEMM: C[row][col] = sum_k A[row][k] * B[col][k]
// A: [rows][K] row-major planes, staged via global_load_lds (XOR-swizzled).
// B: fragment-major blobs (wprep_k layout), loaded global->VGPR per K-step.
// SPLIT=1: dual accumulator f16x2 correction. BK=32; 2x2 waves per block.
// ---------------------------------------------------------------------------
#define AM_ID 0
#define AM_GA 2
#define AM_PA 3
#define EP_QKV 0
#define EP_F32 2
#define EP_HE 3
#define EP_YE 4

template <int SPLIT, int BM, int BN, int AMAP, int EPI>
__global__ void __launch_bounds__(256) gemm_k(
    const f16* __restrict__ Ah, const f16* __restrict__ Al,
    const f16* __restrict__ Bh, const f16* __restrict__ Bl,
    void* __restrict__ o0, void* __restrict__ o1,
    const float* __restrict__ bias,
    int Kd, int strideA, int bExpStride,
    const int* __restrict__ list, const int* __restrict__ bases,
    const int* __restrict__ counts) {
  constexpr int PL = SPLIT ? 2 : 1;
  constexpr int MT = BM / 32;            // 16-row tiles per wave
  constexpr int NT = BN / 32;            // 16-col tiles per wave
  constexpr int AIT = BM / 64;           // A staging iters (256 thr, 16B units)
  const int e = blockIdx.z;
  int cnt = 0, base0 = 0;
  if constexpr (AMAP == AM_GA || AMAP == AM_PA) {
    cnt = counts[e]; base0 = bases[e];
    if ((int)blockIdx.y * BM >= cnt) return;
    Bh += (size_t)e * bExpStride;
    if constexpr (SPLIT) Bl += (size_t)e * bExpStride;
  }
  __shared__ f16 sA[PL][BM * 32];
  const int n0 = blockIdx.x * BN, r0 = blockIdx.y * BM;
  const int tid = threadIdx.x, lane = tid & 63, wv = tid >> 6;
  const int wm = (wv >> 1) * (BM / 2), wn = (wv & 1) * (BN / 2);
  const int bKt = Kd >> 5;
  const int gnt0 = (n0 + wn) >> 4;

  f32x4 accM[MT][NT], accC[MT][NT];
#pragma unroll
  for (int i = 0; i < MT; i++)
#pragma unroll
    for (int j = 0; j < NT; j++) { accM[i][j] = zero4(); accC[i][j] = zero4(); }

  // precompute A staging source rows/cols (constant over K loop)
  int aRow[AIT], aCu[AIT];
#pragma unroll
  for (int c = 0; c < AIT; c++) {
    int u = c * 256 + tid;
    int r = u >> 2, cu = u & 3;
    aCu[c] = ((cu ^ ((r >> 1) & 3)) << 3);
    int rr = r0 + r;
    int g;
    if constexpr (AMAP == AM_ID) g = rr;
    else if constexpr (AMAP == AM_GA) g = (rr < cnt) ? list[base0 + rr] : 0;
    else g = base0 + rr;
    aRow[c] = g;
  }

  for (int k0 = 0; k0 < Kd; k0 += 32) {
    const int kt = k0 >> 5;
    // B fragments: direct global->VGPR, 1KB coalesced per load (frag-major)
    f16x8 bh[NT], bl[NT];
#pragma unroll
    for (int nt = 0; nt < NT; nt++) {
      size_t bi = ((size_t)(gnt0 + nt) * bKt + kt) * 512 + lane * 8;
      bh[nt] = *(const f16x8*)&Bh[bi];
      if constexpr (SPLIT) bl[nt] = *(const f16x8*)&Bl[bi];
    }
    // A tiles: async-stage to LDS (linear dest, pre-swizzled source col)
#pragma unroll
    for (int c = 0; c < AIT; c++) {
      int u = c * 256 + tid;
      gload_lds16(&Ah[(size_t)aRow[c] * strideA + k0 + aCu[c]], &sA[0][u * 8]);
      if constexpr (SPLIT)
        gload_lds16(&Al[(size_t)aRow[c] * strideA + k0 + aCu[c]], &sA[1][u * 8]);
    }
    __syncthreads();

    f16x8 ah[MT], al[MT];
#pragma unroll
    for (int mt = 0; mt < MT; mt++) {
      int r = wm + mt * 16 + (lane & 15);
      int cu = (lane >> 4) ^ ((r >> 1) & 3);
      ah[mt] = *(const f16x8*)&sA[0][(r * 4 + cu) * 8];
      if constexpr (SPLIT) al[mt] = *(const f16x8*)&sA[1][(r * 4 + cu) * 8];
    }
#pragma unroll
    for (int nt = 0; nt < NT; nt++) {
#pragma unroll
      for (int mt = 0; mt < MT; mt++) {
        accM[mt][nt] = MFMA16(ah[mt], bh[nt], accM[mt][nt]);
        if constexpr (SPLIT) {
          accC[mt][nt] = MFMA16(ah[mt], bl[nt], accC[mt][nt]);
          accC[mt][nt] = MFMA16(al[mt], bh[nt], accC[mt][nt]);
        }
      }
    }
    __syncthreads();
  }

  // epilogue
#pragma unroll
  for (int mt = 0; mt < MT; mt++)
#pragma unroll
    for (int nt = 0; nt < NT; nt++)
#pragma unroll
      for (int rg = 0; rg < 4; rg++) {
        int row = r0 + wm + mt * 16 + ((lane >> 4) << 2) + rg;
        int col = n0 + wn + nt * 16 + (lane & 15);
        float v = accM[mt][nt][rg];
        if constexpr (SPLIT) v += accC[mt][nt][rg] * LO_INV;
        if constexpr (EPI == EP_QKV) {
          // rows are h_all rows [b*1024+pos]; cols: [0,1024)=Q, [1024,2048)=K,
          // [2048,3072)=V (stored transposed). Q only valid for pos>=512.
          f16* QH = (f16*)o0;
          f16* QL = QH + (1u << 21);
          f16* KH = QL + (1u << 21);
          f16* KL = KH + (1u << 22);
          f16* VTH = KL + (1u << 22);
          f16* VTL = VTH + (1u << 22);
          int b = row >> 10, pos = row & 1023;
          int seg = col >> 10, hd = (col >> 7) & 7, d = col & 127;
          f16 hh, ll; split2(v, &hh, &ll);
          if (seg == 0) {
            if (pos >= 512) {
              size_t ad = ((size_t)((((b << 3) + hd) << 9) + (pos - 512))) * 128 + d;
              QH[ad] = hh; QL[ad] = ll;
            }
          } else if (seg == 1) {
            size_t ad = ((size_t)((((b << 3) + hd) << 10) + pos)) * 128 + d;
            KH[ad] = hh; KL[ad] = ll;
          } else {
            size_t ad = ((size_t)((((b << 3) + hd) << 7) + d)) * 1024 + pos;
            VTH[ad] = hh; VTL[ad] = ll;
          }
        } else if constexpr (EPI == EP_F32) {
          ((float*)o0)[(size_t)row * 1024 + col] = v;
        } else if constexpr (EPI == EP_HE) {
          if (row < cnt) {
            float t = v + bias[(e << 11) + col];
            ((f16*)o0)[(size_t)(base0 + row) * 2048 + col] = (f16)fmaxf(t, 0.f);
          }
        } else if constexpr (EPI == EP_YE) {
          if (row < cnt)
            ((float*)o0)[(size_t)(base0 + row) * 1024 + col] = v + bias[(e << 10) + col];
        }
      }
}

// ---------------------------------------------------------------------------
// Windowed relative-position attention.
// One block = (b*8+head, 32 query rows). Window = 544 keys (32+512).
// S[32][548] in LDS: fp32 scores -> packed split-f16 probabilities in place.
// ---------------------------------------------------------------------------
__device__ __forceinline__ void unpack_p(const unsigned* sp, f16x8* hi, f16x8* lo) {
  i32x4 u0 = *(const i32x4*)sp;
  i32x4 u1 = *(const i32x4*)(sp + 4);
  i32x4 h, l;
  h[0] = (u0[0] & 0xffff) | (u0[1] << 16);
  h[1] = (u0[2] & 0xffff) | (u0[3] << 16);
  h[2] = (u1[0] & 0xffff) | (u1[1] << 16);
  h[3] = (u1[2] & 0xffff) | (u1[3] << 16);
  l[0] = (int)(((unsigned)u0[0] >> 16) | ((unsigned)u0[1] & 0xffff0000u));
  l[1] = (int)(((unsigned)u0[2] >> 16) | ((unsigned)u0[3] & 0xffff0000u));
  l[2] = (int)(((unsigned)u1[0] >> 16) | ((unsigned)u1[1] & 0xffff0000u));
  l[3] = (int)(((unsigned)u1[2] >> 16) | ((unsigned)u1[3] & 0xffff0000u));
  *hi = __builtin_bit_cast(f16x8, h);
  *lo = __builtin_bit_cast(f16x8, l);
}

__global__ void __launch_bounds__(256) attn_k(
    const f16* __restrict__ qh_, const f16* __restrict__ ql_,
    const f16* __restrict__ kh_, const f16* __restrict__ kl_,
    const f16* __restrict__ ph_, const f16* __restrict__ pl_,
    const f16* __restrict__ vh_, const f16* __restrict__ vl_,
    f16* __restrict__ oh_, f16* __restrict__ ol_) {
  __shared__ float S[32][548];
  const int bh = blockIdx.y;
  const int m0 = blockIdx.x * 32;
  const int tid = threadIdx.x, lane = tid & 63, wv = tid >> 6;
  const int lr = lane & 15, lgp = lane >> 4;

  // Q fragments (held in registers)
  f16x8 qh[2][4], ql[2][4];
  {
    const size_t qbase = ((size_t)bh * 512 + m0) * 128;
#pragma unroll
    for (int mt = 0; mt < 2; mt++)
#pragma unroll
      for (int kb = 0; kb < 4; kb++) {
        size_t off = qbase + (size_t)(mt * 16 + lr) * 128 + kb * 32 + lgp * 8;
        qh[mt][kb] = *(const f16x8*)&qh_[off];
        ql[mt][kb] = *(const f16x8*)&ql_[off];
      }
  }

  // phase 1: content scores  S[m][j] = q[m] . k[m0+j]
  {
    const size_t kbase = ((size_t)bh * 1024 + m0) * 128;
    int ntB = (wv < 2) ? wv * 9 : 18 + (wv - 2) * 8;
    int ntE = ntB + ((wv < 2) ? 9 : 8);
    for (int nt = ntB; nt < ntE; ++nt) {
      f16x8 kh[4], kl[4];
#pragma unroll
      for (int kb = 0; kb < 4; kb++) {
        size_t off = kbase + (size_t)(nt * 16 + lr) * 128 + kb * 32 + lgp * 8;
        kh[kb] = *(const f16x8*)&kh_[off];
        kl[kb] = *(const f16x8*)&kl_[off];
      }
      f32x4 aM[2], aC[2];
      aM[0] = zero4(); aM[1] = zero4(); aC[0] = zero4(); aC[1] = zero4();
#pragma unroll
      for (int kb = 0; kb < 4; kb++)
#pragma unroll
        for (int mt = 0; mt < 2; mt++) {
          aM[mt] = MFMA16(qh[mt][kb], kh[kb], aM[mt]);
          aC[mt] = MFMA16(qh[mt][kb], kl[kb], aC[mt]);
          aC[mt] = MFMA16(ql[mt][kb], kh[kb], aC[mt]);
        }
#pragma unroll
      for (int mt = 0; mt < 2; mt++)
#pragma unroll
        for (int rg = 0; rg < 4; rg++) {
          int m = mt * 16 + lgp * 4 + rg;
          S[m][nt * 16 + lr] = aM[mt][rg] + aC[mt][rg] * LO_INV;
        }
    }
  }
  __syncthreads();

  // phase 2: positional scores  S[m][m+l] += q[m] . pe[l]
  {
    for (int lt = wv * 8; lt < wv * 8 + 8; ++lt) {
      f16x8 eh[4], el[4];
#pragma unroll
      for (int kb = 0; kb < 4; kb++) {
        size_t off = (size_t)(lt * 16 + lr) * 128 + kb * 32 + lgp * 8;
        eh[kb] = *(const f16x8*)&ph_[off];
        el[kb] = *(const f16x8*)&pl_[off];
      }
      f32x4 aM[2], aC[2];
      aM[0] = zero4(); aM[1] = zero4(); aC[0] = zero4(); aC[1] = zero4();
#pragma unroll
      for (int kb = 0; kb < 4; kb++)
#pragma unroll
        for (int mt = 0; mt < 2; mt++) {
          aM[mt] = MFMA16(qh[mt][kb], eh[kb], aM[mt]);
          aC[mt] = MFMA16(qh[mt][kb], el[kb], aC[mt]);
          aC[mt] = MFMA16(ql[mt][kb], eh[kb], aC[mt]);
        }
#pragma unroll
      for (int mt = 0; mt < 2; mt++)
#pragma unroll
        for (int rg = 0; rg < 4; rg++) {
          int m = mt * 16 + lgp * 4 + rg;
          int lc = lt * 16 + lr;
          S[m][m + lc] += aM[mt][rg] + aC[mt][rg] * LO_INV;
        }
    }
  }
  __syncthreads();

  // phase 3: softmax over each row's valid window [m, m+512), write packed split P
  {
    const float scl = 0.08838834764831843f;  // 1/sqrt(128)
    for (int rr = 0; rr < 8; ++rr) {
      int m = wv * 8 + rr;
      float mx = -3.0e38f;
#pragma unroll
      for (int it = 0; it < 9; ++it) {
        int j = it * 64 + lane;
        if (j < 544 && j >= m && j < m + 512) mx = fmaxf(mx, S[m][j]);
      }
#pragma unroll
      for (int o = 32; o > 0; o >>= 1) mx = fmaxf(mx, __shfl_xor(mx, o));
      float pv[9]; float sm = 0.f;
#pragma unroll
      for (int it = 0; it < 9; ++it) {
        int j = it * 64 + lane;
        float p = 0.f;
        if (j < 544 && j >= m && j < m + 512) p = expf((S[m][j] - mx) * scl);
        pv[it] = p; sm += p;
      }
#pragma unroll
      for (int o = 32; o > 0; o >>= 1) sm += __shfl_xor(sm, o);
      float inv = 1.0f / sm;
#pragma unroll
      for (int it = 0; it < 9; ++it) {
        int j = it * 64 + lane;
        if (j < 544) {
          float pn = pv[it] * inv;
          f16 hh, ll; split2(pn, &hh, &ll);
          unsigned pk = (unsigned)__builtin_bit_cast(unsigned short, hh) |
                        ((unsigned)__builtin_bit_cast(unsigned short, ll) << 16);
          ((unsigned*)&S[m][0])[j] = pk;
        }
      }
    }
  }
  __syncthreads();

  // phase 4: O[m][d] = sum_j P[m][j] * V[m0+j][d]   (V stored transposed [d][pos])
  f32x4 accM[2][2], accC[2][2];
#pragma unroll
  for (int i = 0; i < 2; i++)
#pragma unroll
    for (int j = 0; j < 2; j++) { accM[i][j] = zero4(); accC[i][j] = zero4(); }
  for (int kb = 0; kb < 17; ++kb) {
    f16x8 pah[2], pal[2];
#pragma unroll
    for (int mt = 0; mt < 2; mt++) {
      const unsigned* sp = (const unsigned*)&S[mt * 16 + lr][0] + kb * 32 + lgp * 8;
      unpack_p(sp, &pah[mt], &pal[mt]);
    }
#pragma unroll
    for (int ntl = 0; ntl < 2; ++ntl) {
      int d = wv * 32 + ntl * 16 + lr;
      size_t off = ((size_t)bh * 128 + d) * 1024 + m0 + kb * 32 + lgp * 8;
      f16x8 vh = *(const f16x8*)&vh_[off];
      f16x8 vl = *(const f16x8*)&vl_[off];
#pragma unroll
      for (int mt = 0; mt < 2; mt++) {
        accM[mt][ntl] = MFMA16(pah[mt], vh, accM[mt][ntl]);
        accC[mt][ntl] = MFMA16(pah[mt], vl, accC[mt][ntl]);
        accC[mt][ntl] = MFMA16(pal[mt], vh, accC[mt][ntl]);
      }
    }
  }
  const int b = bh >> 3, hd = bh & 7;
#pragma unroll
  for (int mt = 0; mt < 2; mt++)
#pragma unroll
    for (int ntl = 0; ntl < 2; ntl++)
#pragma unroll
      for (int rg = 0; rg < 4; rg++) {
        int m = mt * 16 + lgp * 4 + rg;
        int d = wv * 32 + ntl * 16 + lr;
        float v = accM[mt][ntl][rg] + accC[mt][ntl][rg] * LO_INV;
        size_t ad = ((size_t)(b * 512 + m0 + m)) * 1024 + hd * 128 + d;
        f16 hh, ll; split2(v, &hh, &ll);
        oh_[ad] = hh; ol_[ad] = ll;
      }
}

// ---------------------------------------------------------------------------
// LayerNorm helpers / kernels (fp32)
// ---------------------------------------------------------------------------
__device__ __forceinline__ float blk_sum(float v, float* red) {
#pragma unroll
  for (int o = 32; o > 0; o >>= 1) v += __shfl_xor(v, o);
  int wv = threadIdx.x >> 6;
  if ((threadIdx.x & 63) == 0) red[wv] = v;
  __syncthreads();
  float r = red[0] + red[1] + red[2] + red[3];
  __syncthreads();
  return r;
}

__global__ void __launch_bounds__(256) ln1_k(const float* __restrict__ h,
                                             const float* __restrict__ ap,
                                             const float* __restrict__ g,
                                             const float* __restrict__ bb,
                                             float* __restrict__ h1,
                                             f16* __restrict__ h1h) {
  int row = blockIdx.x;
  __shared__ float red[4];
  float4 hv = ((const float4*)(h + (size_t)row * 1024))[threadIdx.x];
  float4 av = ((const float4*)(ap + (size_t)row * 1024))[threadIdx.x];
  float4 x; x.x = hv.x + av.x; x.y = hv.y + av.y; x.z = hv.z + av.z; x.w = hv.w + av.w;
  float s = x.x + x.y + x.z + x.w;
  s = blk_sum(s, red);
  float mean = s * (1.0f / 1024.0f);
  float4 d; d.x = x.x - mean; d.y = x.y - mean; d.z = x.z - mean; d.w = x.w - mean;
  float s2 = d.x * d.x + d.y * d.y + d.z * d.z + d.w * d.w;
  s2 = blk_sum(s2, red);
  float var = s2 * (1.0f / 1024.0f);
  float inv = 1.0f / sqrtf(var + 1e-5f);
  float4 gv = ((const float4*)g)[threadIdx.x];
  float4 bv = ((const float4*)bb)[threadIdx.x];
  float4 y; y.x = d.x * inv * gv.x + bv.x; y.y = d.y * inv * gv.y + bv.y;
  y.z = d.z * inv * gv.z + bv.z; y.w = d.w * inv * gv.w + bv.w;
  ((float4*)(h1 + (size_t)row * 1024))[threadIdx.x] = y;
  f16x4 yh; yh[0] = (f16)y.x; yh[1] = (f16)y.y; yh[2] = (f16)y.z; yh[3] = (f16)y.w;
  *(f16x4*)&h1h[(size_t)row * 1024 + threadIdx.x * 4] = yh;
}

// ---------------------------------------------------------------------------
// Gate: logits = h1 @ gate_W + gate_b, top-2, softmax, counts
// ---------------------------------------------------------------------------
__global__ void __launch_bounds__(256) gate_k(const float* __restrict__ h1,
                                              const float* __restrict__ gW,
                                              const float* __restrict__ gb,
                                              float* __restrict__ outIdx,
                                              float* __restrict__ sc,
                                              int* __restrict__ te,
                                              int* __restrict__ ctrl) {
  int t = blockIdx.x * 4 + (threadIdx.x >> 6);
  int lane = threadIdx.x & 63;
  float a0 = 0, a1 = 0, a2 = 0, a3 = 0, a4 = 0, a5 = 0, a6 = 0, a7 = 0;
  for (int i = lane; i < 1024; i += 64) {
    float x = h1[(size_t)t * 1024 + i];
    const float4* w = (const float4*)&gW[i * 8];
    float4 w0 = w[0], w1 = w[1];
    a0 += x * w0.x; a1 += x * w0.y; a2 += x * w0.z; a3 += x * w0.w;
    a4 += x * w1.x; a5 += x * w1.y; a6 += x * w1.z; a7 += x * w1.w;
  }
  float av[8] = {a0, a1, a2, a3, a4, a5, a6, a7};
#pragma unroll
  for (int e = 0; e < 8; e++)
#pragma unroll
    for (int o = 32; o > 0; o >>= 1) av[e] += __shfl_xor(av[e], o);
  if (lane == 0) {
#pragma unroll
    for (int e = 0; e < 8; e++) av[e] += gb[e];
    int i0 = 0; float v0 = av[0];
#pragma unroll
    for (int e = 1; e < 8; e++) if (av[e] > v0) { v0 = av[e]; i0 = e; }
    int i1 = -1; float v1 = -3.0e38f;
#pragma unroll
    for (int e = 0; e < 8; e++) if (e != i0 && av[e] > v1) { v1 = av[e]; i1 = e; }
    float ex = expf(v1 - v0);
    float den = 1.0f + ex;
    outIdx[t * 2] = (float)i0; outIdx[t * 2 + 1] = (float)i1;
    sc[t * 2] = 1.0f / den; sc[t * 2 + 1] = ex / den;
    te[t * 2] = i0; te[t * 2 + 1] = i1;
    atomicAdd(&ctrl[i0], 1); atomicAdd(&ctrl[i1], 1);
  }
}

__global__ void scan_k(int* ctrl) {
  if (threadIdx.x == 0 && blockIdx.x == 0) {
    int s = 0;
    for (int e = 0; e < 8; e++) { ctrl[8 + e] = s; s += ctrl[e]; }
  }
}

__global__ void __launch_bounds__(256) scatter_k(const int* __restrict__ te,
                                                 int* ctrl,
                                                 int* __restrict__ list,
                                                 int* __restrict__ ppos) {
  int t = blockIdx.x * 256 + threadIdx.x;
  if (t >= 2048) return;
#pragma unroll
  for (int s = 0; s < 2; s++) {
    int e = te[t * 2 + s];
    int pos = atomicAdd(&ctrl[16 + e], 1);
    int pr = ctrl[8 + e] + pos;
    list[pr] = t;
    ppos[t * 2 + s] = pr;
  }
}

// ---------------------------------------------------------------------------
// Combine MoE outputs + final LayerNorm
// ---------------------------------------------------------------------------
__global__ void __launch_bounds__(256) comb_ln2_k(const float* __restrict__ h1,
                                                  const float* __restrict__ ye,
                                                  const float* __restrict__ sc,
                                                  const int* __restrict__ ppos,
                                                  const float* __restrict__ g,
                                                  const float* __restrict__ bb,
                                                  float* __restrict__ out) {
  int row = blockIdx.x;
  __shared__ float red[4];
  int p0 = ppos[row * 2], p1 = ppos[row * 2 + 1];
  float s0 = sc[row * 2], s1 = sc[row * 2 + 1];
  float4 a = ((const float4*)(h1 + (size_t)row * 1024))[threadIdx.x];
  float4 y0 = ((const float4*)(ye + (size_t)p0 * 1024))[threadIdx.x];
  float4 y1 = ((const float4*)(ye + (size_t)p1 * 1024))[threadIdx.x];
  float4 x;
  x.x = a.x + s0 * y0.x + s1 * y1.x; x.y = a.y + s0 * y0.y + s1 * y1.y;
  x.z = a.z + s0 * y0.z + s1 * y1.z; x.w = a.w + s0 * y0.w + s1 * y1.w;
  float s = x.x + x.y + x.z + x.w;
  s = blk_sum(s, red);
  float mean = s * (1.0f / 1024.0f);
  float4 d; d.x = x.x - mean; d.y = x.y - mean; d.z = x.z - mean; d.w = x.w - mean;
  float s2 = d.x * d.x + d.y * d.y + d.z * d.z + d.w * d.w;
  s2 = blk_sum(s2, red);
  float var = s2 * (1.0f / 1024.0f);
  float inv = 1.0f / sqrtf(var + 1e-5f);
  float4 gv = ((const float4*)g)[threadIdx.x];
  float4 bv = ((const float4*)bb)[threadIdx.x];
  float4 y; y.x = d.x * inv * gv.x + bv.x; y.y = d.y * inv * gv.y + bv.y;
  y.z = d.z * inv * gv.z + bv.z; y.w = d.w * inv * gv.w + bv.w;
  ((float4*)(out + (size_t)row * 1024))[threadIdx.x] = y;
}

// ---------------------------------------------------------------------------
// Host launch
// ---------------------------------------------------------------------------
extern "C" void kernel_launch(void* const* d_in, const int* in_sizes, int n_in,
                              void* d_out, int out_size, void* d_ws, size_t ws_size,
                              hipStream_t stream) {
  const float* h   = (const float*)d_in[0];
  const float* hc  = (const float*)d_in[1];
  const float* pe  = (const float*)d_in[2];
  const float* Wq  = (const float*)d_in[3];
  const float* Wk  = (const float*)d_in[4];
  const float* Wv  = (const float*)d_in[5];
  const float* Wo  = (const float*)d_in[6];
  const float* g1  = (const float*)d_in[7];
  const float* b1n = (const float*)d_in[8];
  const float* gW  = (const float*)d_in[9];
  const float* gb  = (const float*)d_in[10];
  const float* W1  = (const float*)d_in[11];
  const float* b1e = (const float*)d_in[12];
  const float* W2  = (const float*)d_in[13];
  const float* b2e = (const float*)d_in[14];
  const float* g2  = (const float*)d_in[15];
  const float* b2n = (const float*)d_in[16];
  float* out = (float*)d_out;
  float* outIdx = out + 2097152;

  char* w = (char*)d_ws;
  size_t off = 0;
  auto alloc = [&](size_t bytes) -> char* {
    char* p = w + off;
    off += (bytes + 255) & ~(size_t)255;
    return p;
  };
  int*   ctrl    = (int*)alloc(128);
  f16*   hallH   = (f16*)alloc(4096ull * 1024 * 2);
  f16*   hallL   = (f16*)alloc(4096ull * 1024 * 2);
  f16*   WqkvtH  = (f16*)alloc(3072ull * 1024 * 2);   // frag-major
  f16*   WqkvtL  = (f16*)alloc(3072ull * 1024 * 2);
  f16*   WotH    = (f16*)alloc(1024ull * 1024 * 2);   // frag-major
  f16*   WotL    = (f16*)alloc(1024ull * 1024 * 2);
  f16*   peH     = (f16*)alloc(512ull * 128 * 2);
  f16*   peL     = (f16*)alloc(512ull * 128 * 2);
  // contiguous qkv block; offsets hard-coded in EP_QKV epilogue
  f16*   qkv     = (f16*)alloc(20971520ull * 2);
  f16*   qH  = qkv;
  f16*   qL  = qH + (1u << 21);
  f16*   kH  = qL + (1u << 21);
  f16*   kL  = kH + (1u << 22);
  f16*   vtH = kL + (1u << 22);
  f16*   vtL = vtH + (1u << 22);
  f16*   attH  = (f16*)alloc(2097152ull * 2);
  f16*   attL  = (f16*)alloc(2097152ull * 2);
  float* aproj = (float*)alloc(2097152ull * 4);
  float* h1    = (float*)alloc(2097152ull * 4);
  f16*   h1h   = (f16*)alloc(2097152ull * 2);
  f16*   W1t   = (f16*)alloc(16777216ull * 2);        // frag-major per expert
  f16*   W2t   = (f16*)alloc(16777216ull * 2);
  f16*   he    = (f16*)alloc(4224ull * 2048 * 2);
  float* ye    = (float*)alloc(4224ull * 1024 * 4);
  float* scb   = (float*)alloc(2048ull * 2 * 4);
  int*   te    = (int*)alloc(2048ull * 2 * 4);
  int*   ppos  = (int*)alloc(2048ull * 2 * 4);
  int*   list  = (int*)alloc(4096ull * 4);
  (void)in_sizes; (void)n_in; (void)out_size; (void)ws_size;

  hipMemsetAsync(ctrl, 0, 128, stream);

  // casts / weight prep (frag-major)
  cast_hall_k<<<2048, 256, 0, stream>>>(h, hc, hallH, hallL);
  wprep_k<1><<<dim3(32, 32, 1), 256, 0, stream>>>(Wq, WqkvtH, WqkvtL, 1024, 1024);
  wprep_k<1><<<dim3(32, 32, 1), 256, 0, stream>>>(Wk, WqkvtH + 1048576, WqkvtL + 1048576, 1024, 1024);
  wprep_k<1><<<dim3(32, 32, 1), 256, 0, stream>>>(Wv, WqkvtH + 2097152, WqkvtL + 2097152, 1024, 1024);
  wprep_k<1><<<dim3(32, 32, 1), 256, 0, stream>>>(Wo, WotH, WotL, 1024, 1024);
  transpose_cast_k<1><<<dim3(16, 4, 1), 256, 0, stream>>>(pe, peH, peL, 128, 512);
  wprep_k<0><<<dim3(64, 32, 8), 256, 0, stream>>>(W1, W1t, nullptr, 1024, 2048);
  wprep_k<0><<<dim3(32, 64, 8), 256, 0, stream>>>(W2, W2t, nullptr, 2048, 1024);

  // merged QKV projection over h_all (N=3072): 1536 blocks, 128x64 split tile
  gemm_k<1, 128, 64, AM_ID, EP_QKV><<<dim3(48, 32, 1), 256, 0, stream>>>(
      hallH, hallL, WqkvtH, WqkvtL, qkv, nullptr, nullptr, 1024, 1024, 0,
      nullptr, nullptr, nullptr);

  // attention
  attn_k<<<dim3(16, 32, 1), 256, 0, stream>>>(qH, qL, kH, kL, peH, peL, vtH, vtL, attH, attL);

  // output projection + LN1 (64x64 tile: 512 blocks)
  gemm_k<1, 64, 64, AM_ID, EP_F32><<<dim3(16, 32, 1), 256, 0, stream>>>(
      attH, attL, WotH, WotL, aproj, nullptr, nullptr, 1024, 1024, 0,
      nullptr, nullptr, nullptr);
  ln1_k<<<2048, 256, 0, stream>>>(h, aproj, g1, b1n, h1, h1h);

  // gate + routing
  gate_k<<<512, 256, 0, stream>>>(h1, gW, gb, outIdx, scb, te, ctrl);
  scan_k<<<1, 64, 0, stream>>>(ctrl);
  scatter_k<<<8, 256, 0, stream>>>(te, ctrl, list, ppos);

  // expert FFNs (64-row tiles)
  gemm_k<0, 64, 128, AM_GA, EP_HE><<<dim3(16, 32, 8), 256, 0, stream>>>(
      h1h, nullptr, W1t, nullptr, he, nullptr, b1e, 1024, 1024, 2048 * 1024,
      list, ctrl + 8, ctrl);
  gemm_k<0, 64, 128, AM_PA, EP_YE><<<dim3(8, 32, 8), 256, 0, stream>>>(
      he, nullptr, W2t, nullptr, ye, nullptr, b2e, 2048, 2048, 1024 * 2048,
      nullptr, ctrl + 8, ctrl);

  // combine + LN2
  comb_ln2_k<<<2048, 256, 0, stream>>>(h1, ye, scb, ppos, g2, b2n, out);
}

// Round 7
// 653.415 us; speedup vs baseline: 1.0883x; 1.0178x over previous
//
#include <hip/hip_runtime.h>
#include <hip/hip_bf16.h>
#include <stdint.h>

// ---------------------------------------------------------------------------
// TransformerSeqLayer: rel-pos sliding-window attention + post-LN + top-2 MoE
// All heavy matmuls on MFMA f16 16x16x32.
// Pre-gate path uses f16x2 split (hi + lo*2^-11, lo stored pre-scaled by 2^11)
// with dual accumulators => ~2^-22 relative error so top_idx matches fp32 ref.
// Round 7: 2-phase software pipeline in gemm_k. R5/R6 falsified "staging
// mechanism" and "LDS port" theories (util pinned at 26% both ways); residual
// is the per-K-step vmcnt(0) drain at __syncthreads with zero load/compute
// overlap (~340 exposed cyc/step). Now: dbuf sA + dual B reg sets, prefetch
// t+1 before compute t, one barrier per step. B stays global->VGPR frag-major.
// ---------------------------------------------------------------------------

typedef _Float16 f16;
typedef _Float16 f16x8 __attribute__((ext_vector_type(8)));
typedef _Float16 f16x4 __attribute__((ext_vector_type(4)));
typedef float    f32x4 __attribute__((ext_vector_type(4)));
typedef int      i32x4 __attribute__((ext_vector_type(4)));

#define MFMA16(a, b, c) __builtin_amdgcn_mfma_f32_16x16x32_f16((a), (b), (c), 0, 0, 0)
#define LO_SCALE 2048.0f
#define LO_INV   4.8828125e-4f   // 1/2048

__device__ __forceinline__ void split2(float x, f16* h, f16* l) {
  f16 hh = (f16)x;
  *h = hh;
  *l = (f16)((x - (float)hh) * LO_SCALE);
}

__device__ __forceinline__ f32x4 zero4() {
  f32x4 z; z[0] = 0.f; z[1] = 0.f; z[2] = 0.f; z[3] = 0.f; return z;
}

// async 16B global -> LDS (wave-uniform base + lane*16 dest; per-lane source)
__device__ __forceinline__ void gload_lds16(const void* g, void* l) {
  __builtin_amdgcn_global_load_lds((__attribute__((address_space(1))) void*)g,
                                   (__attribute__((address_space(3))) void*)l,
                                   16, 0, 0);
}

// ---------------------------------------------------------------------------
// Cast h_all = concat(h_cache, h) -> split planes [B*1024][1024]
// ---------------------------------------------------------------------------
__global__ void __launch_bounds__(256) cast_hall_k(const float* __restrict__ h,
                                                   const float* __restrict__ hc,
                                                   f16* __restrict__ hi,
                                                   f16* __restrict__ lo) {
  int c = blockIdx.x * 256 + threadIdx.x;   // chunk of 8 elems
  int e0 = c * 8;
  int row = e0 >> 10;
  int col = e0 & 1023;
  int b = row >> 10, pos = row & 1023;
  const float* src = (pos < 512) ? (hc + (size_t)((b << 9) + pos) * 1024 + col)
                                 : (h  + (size_t)((b << 9) + (pos - 512)) * 1024 + col);
  float4 v0 = ((const float4*)src)[0];
  float4 v1 = ((const float4*)src)[1];
  float xs[8] = {v0.x, v0.y, v0.z, v0.w, v1.x, v1.y, v1.z, v1.w};
  f16x8 vh, vl;
#pragma unroll
  for (int i = 0; i < 8; i++) { f16 a, bb; split2(xs[i], &a, &bb); vh[i] = a; vl[i] = bb; }
  *(f16x8*)&hi[e0] = vh;
  *(f16x8*)&lo[e0] = vl;
}

// ---------------------------------------------------------------------------
// Weight prep: fp32 W[k][n] -> MFMA fragment-major f16 planes.
// Blob layout: B'[gnt][kt][lane][8], gnt = n/16, kt = k/32, lane = lgp*16+lr;
// element (lane,j) = W[k0 + lgp*8 + j][n0 + lr].  One wave load = 1KB coalesced.
// ---------------------------------------------------------------------------
template <int SPLIT>
__global__ void __launch_bounds__(256) wprep_k(const float* __restrict__ in,
                                               f16* __restrict__ oh,
                                               f16* __restrict__ ol,
                                               int K, int N) {
  in += (size_t)blockIdx.z * K * N;
  oh += (size_t)blockIdx.z * K * N;
  if constexpr (SPLIT) ol += (size_t)blockIdx.z * K * N;
  __shared__ float tile[32][33];
  const int n0 = blockIdx.x * 32, k0 = blockIdx.y * 32;
  {
    int r = threadIdx.x >> 3, c4 = (threadIdx.x & 7) * 4;
    float4 v = *(const float4*)&in[(size_t)(k0 + r) * N + n0 + c4];
    tile[r][c4 + 0] = v.x; tile[r][c4 + 1] = v.y;
    tile[r][c4 + 2] = v.z; tile[r][c4 + 3] = v.w;
  }
  __syncthreads();
  int t = threadIdx.x;
  if constexpr (!SPLIT) { if (t >= 128) return; }
  int half = SPLIT ? (t >> 7) : 0;
  int r = t & 127;
  int nt = r >> 6, lane = r & 63;
  int lr = lane & 15, lgp = lane >> 4;
  f16x8 v;
#pragma unroll
  for (int j = 0; j < 8; j++) {
    float x = tile[lgp * 8 + j][nt * 16 + lr];
    f16 hh, ll; split2(x, &hh, &ll);
    v[j] = half ? ll : hh;
  }
  size_t blob = (((size_t)(n0 >> 4) + nt) * (K >> 5) + (k0 >> 5)) * 512 + lane * 8;
  f16* dst = half ? ol : oh;
  *(f16x8*)&dst[blob] = v;
}

// ---------------------------------------------------------------------------
// Transpose + cast (kept for pe only): in [R][C] fp32 -> out [C][R] f16 split
// ---------------------------------------------------------------------------
template <int SPLIT>
__global__ void __launch_bounds__(256) transpose_cast_k(const float* __restrict__ in,
                                                        f16* __restrict__ oh,
                                                        f16* __restrict__ ol,
                                                        int R, int C) {
  in += (size_t)blockIdx.z * R * C;
  oh += (size_t)blockIdx.z * R * C;
  if constexpr (SPLIT) ol += (size_t)blockIdx.z * R * C;
  __shared__ float tile[32][33];
  int c0 = blockIdx.x * 32, r0 = blockIdx.y * 32;
  int tr = threadIdx.x >> 3, tc = (threadIdx.x & 7) * 4;
  float4 v = *(const float4*)&in[(size_t)(r0 + tr) * C + c0 + tc];
  tile[tr][tc + 0] = v.x; tile[tr][tc + 1] = v.y; tile[tr][tc + 2] = v.z; tile[tr][tc + 3] = v.w;
  __syncthreads();
  int oc = tr;
  int orr = tc;
  f16x4 vh, vl;
#pragma unroll
  for (int i = 0; i < 4; i++) {
    float x = tile[orr + i][oc];
    f16 a, bb; split2(x, &a, &bb);
    vh[i] = a; vl[i] = bb;
  }
  *(f16x4*)&oh[(size_t)(c0 + oc) * R + r0 + orr] = vh;
  if constexpr (SPLIT) *(f16x4*)&ol[(size_t)(c0 + oc) * R + r0 + orr] = vl;
}

// ---------------------------------------------------------------------------
// Generic GEMM, 2-phase pipelined: C[row][col] = sum_k A[row][k] * B[col][k]
// A: [rows][K] row-major planes, double-buffered LDS via global_load_lds.
// B: fragment-major blobs, dual register sets, prefetched one K-step ahead.
// SPLIT=1: dual accumulator f16x2 correction. BK=32; 2x2 waves per block.
// ---------------------------------------------------------------------------
#define AM_ID 0
#define AM_GA 2
#define AM_PA 3
#define EP_QKV 0
#define EP_F32 2
#define EP_HE 3
#define EP_YE 4

template <int SPLIT, int BM, int BN, int AMAP, int EPI>
__global__ void __launch_bounds__(256) gemm_k(
    const f16* __restrict__ Ah, const f16* __restrict__ Al,
    const f16* __restrict__ Bh, const f16* __restrict__ Bl,
    void* __restrict__ o0, void* __restrict__ o1,
    const float* __restrict__ bias,
    int Kd, int strideA, int bExpStride,
    const int* __restrict__ list, const int* __restrict__ bases,
    const int* __restrict__ counts) {
  constexpr int PL = SPLIT ? 2 : 1;
  constexpr int MT = BM / 32;            // 16-row tiles per wave
  constexpr int NT = BN / 32;            // 16-col tiles per wave
  constexpr int AIT = BM / 64;           // A staging iters (256 thr, 16B units)
  const int e = blockIdx.z;
  int cnt = 0, base0 = 0;
  if constexpr (AMAP == AM_GA || AMAP == AM_PA) {
    cnt = counts[e]; base0 = bases[e];
    if ((int)blockIdx.y * BM >= cnt) return;
    Bh += (size_t)e * bExpStride;
    if constexpr (SPLIT) Bl += (size_t)e * bExpStride;
  }
  __shared__ f16 sA[2][PL][BM * 32];
  const int n0 = blockIdx.x * BN, r0 = blockIdx.y * BM;
  const int tid = threadIdx.x, lane = tid & 63, wv = tid >> 6;
  const int wm = (wv >> 1) * (BM / 2), wn = (wv & 1) * (BN / 2);
  const int bKt = Kd >> 5;
  const int gnt0 = (n0 + wn) >> 4;

  f32x4 accM[MT][NT], accC[MT][NT];
#pragma unroll
  for (int i = 0; i < MT; i++)
#pragma unroll
    for (int j = 0; j < NT; j++) { accM[i][j] = zero4(); accC[i][j] = zero4(); }

  // precompute A staging source rows/cols (constant over K loop)
  int aRow[AIT], aCu[AIT];
#pragma unroll
  for (int c = 0; c < AIT; c++) {
    int u = c * 256 + tid;
    int r = u >> 2, cu = u & 3;
    aCu[c] = ((cu ^ ((r >> 1) & 3)) << 3);
    int rr = r0 + r;
    int g;
    if constexpr (AMAP == AM_ID) g = rr;
    else if constexpr (AMAP == AM_GA) g = (rr < cnt) ? list[base0 + rr] : 0;
    else g = base0 + rr;
    aRow[c] = g;
  }

  auto STAGE = [&](int buf, int kt) {
    int k0 = kt << 5;
#pragma unroll
    for (int c = 0; c < AIT; c++) {
      int u = c * 256 + tid;
      gload_lds16(&Ah[(size_t)aRow[c] * strideA + k0 + aCu[c]], &sA[buf][0][u * 8]);
      if constexpr (SPLIT)
        gload_lds16(&Al[(size_t)aRow[c] * strideA + k0 + aCu[c]], &sA[buf][1][u * 8]);
    }
  };
  auto LOADB = [&](f16x8 (&bh)[NT], f16x8 (&bl)[NT], int kt) {
#pragma unroll
    for (int nt = 0; nt < NT; nt++) {
      size_t bi = ((size_t)(gnt0 + nt) * bKt + kt) * 512 + lane * 8;
      bh[nt] = *(const f16x8*)&Bh[bi];
      if constexpr (SPLIT) bl[nt] = *(const f16x8*)&Bl[bi];
    }
  };
  auto COMPUTE = [&](int buf, f16x8 (&bh)[NT], f16x8 (&bl)[NT]) {
    f16x8 ah[MT], al[MT];
#pragma unroll
    for (int mt = 0; mt < MT; mt++) {
      int r = wm + mt * 16 + (lane & 15);
      int cu = (lane >> 4) ^ ((r >> 1) & 3);
      ah[mt] = *(const f16x8*)&sA[buf][0][(r * 4 + cu) * 8];
      if constexpr (SPLIT) al[mt] = *(const f16x8*)&sA[buf][1][(r * 4 + cu) * 8];
    }
#pragma unroll
    for (int nt = 0; nt < NT; nt++) {
#pragma unroll
      for (int mt = 0; mt < MT; mt++) {
        accM[mt][nt] = MFMA16(ah[mt], bh[nt], accM[mt][nt]);
        if constexpr (SPLIT) {
          accC[mt][nt] = MFMA16(ah[mt], bl[nt], accC[mt][nt]);
          accC[mt][nt] = MFMA16(al[mt], bh[nt], accC[mt][nt]);
        }
      }
    }
  };

  f16x8 b0h[NT], b0l[NT], b1h[NT], b1l[NT];
  const int nkt = Kd >> 5;

  // prologue: stage step 0
  STAGE(0, 0);
  LOADB(b0h, b0l, 0);
  __syncthreads();          // vmcnt(0)+lgkmcnt(0) drain + barrier

  for (int kt = 0; kt < nkt; kt += 2) {
    // phase A: prefetch kt+1, compute kt from buf 0
    if (kt + 1 < nkt) { STAGE(1, kt + 1); LOADB(b1h, b1l, kt + 1); }
    COMPUTE(0, b0h, b0l);
    __syncthreads();
    if (kt + 1 < nkt) {
      // phase B: prefetch kt+2, compute kt+1 from buf 1
      if (kt + 2 < nkt) { STAGE(0, kt + 2); LOADB(b0h, b0l, kt + 2); }
      COMPUTE(1, b1h, b1l);
      __syncthreads();
    }
  }

  // epilogue
#pragma unroll
  for (int mt = 0; mt < MT; mt++)
#pragma unroll
    for (int nt = 0; nt < NT; nt++)
#pragma unroll
      for (int rg = 0; rg < 4; rg++) {
        int row = r0 + wm + mt * 16 + ((lane >> 4) << 2) + rg;
        int col = n0 + wn + nt * 16 + (lane & 15);
        float v = accM[mt][nt][rg];
        if constexpr (SPLIT) v += accC[mt][nt][rg] * LO_INV;
        if constexpr (EPI == EP_QKV) {
          // rows are h_all rows [b*1024+pos]; cols: [0,1024)=Q, [1024,2048)=K,
          // [2048,3072)=V (stored transposed). Q only valid for pos>=512.
          f16* QH = (f16*)o0;
          f16* QL = QH + (1u << 21);
          f16* KH = QL + (1u << 21);
          f16* KL = KH + (1u << 22);
          f16* VTH = KL + (1u << 22);
          f16* VTL = VTH + (1u << 22);
          int b = row >> 10, pos = row & 1023;
          int seg = col >> 10, hd = (col >> 7) & 7, d = col & 127;
          f16 hh, ll; split2(v, &hh, &ll);
          if (seg == 0) {
            if (pos >= 512) {
              size_t ad = ((size_t)((((b << 3) + hd) << 9) + (pos - 512))) * 128 + d;
              QH[ad] = hh; QL[ad] = ll;
            }
          } else if (seg == 1) {
            size_t ad = ((size_t)((((b << 3) + hd) << 10) + pos)) * 128 + d;
            KH[ad] = hh; KL[ad] = ll;
          } else {
            size_t ad = ((size_t)((((b << 3) + hd) << 7) + d)) * 1024 + pos;
            VTH[ad] = hh; VTL[ad] = ll;
          }
        } else if constexpr (EPI == EP_F32) {
          ((float*)o0)[(size_t)row * 1024 + col] = v;
        } else if constexpr (EPI == EP_HE) {
          if (row < cnt) {
            float t = v + bias[(e << 11) + col];
            ((f16*)o0)[(size_t)(base0 + row) * 2048 + col] = (f16)fmaxf(t, 0.f);
          }
        } else if constexpr (EPI == EP_YE) {
          if (row < cnt)
            ((float*)o0)[(size_t)(base0 + row) * 1024 + col] = v + bias[(e << 10) + col];
        }
      }
}

// ---------------------------------------------------------------------------
// Windowed relative-position attention.
// One block = (b*8+head, 32 query rows). Window = 544 keys (32+512).
// S[32][548] in LDS: fp32 scores -> packed split-f16 probabilities in place.
// ---------------------------------------------------------------------------
__device__ __forceinline__ void unpack_p(const unsigned* sp, f16x8* hi, f16x8* lo) {
  i32x4 u0 = *(const i32x4*)sp;
  i32x4 u1 = *(const i32x4*)(sp + 4);
  i32x4 h, l;
  h[0] = (u0[0] & 0xffff) | (u0[1] << 16);
  h[1] = (u0[2] & 0xffff) | (u0[3] << 16);
  h[2] = (u1[0] & 0xffff) | (u1[1] << 16);
  h[3] = (u1[2] & 0xffff) | (u1[3] << 16);
  l[0] = (int)(((unsigned)u0[0] >> 16) | ((unsigned)u0[1] & 0xffff0000u));
  l[1] = (int)(((unsigned)u0[2] >> 16) | ((unsigned)u0[3] & 0xffff0000u));
  l[2] = (int)(((unsigned)u1[0] >> 16) | ((unsigned)u1[1] & 0xffff0000u));
  l[3] = (int)(((unsigned)u1[2] >> 16) | ((unsigned)u1[3] & 0xffff0000u));
  *hi = __builtin_bit_cast(f16x8, h);
  *lo = __builtin_bit_cast(f16x8, l);
}

__global__ void __launch_bounds__(256) attn_k(
    const f16* __restrict__ qh_, const f16* __restrict__ ql_,
    const f16* __restrict__ kh_, const f16* __restrict__ kl_,
    const f16* __restrict__ ph_, const f16* __restrict__ pl_,
    const f16* __restrict__ vh_, const f16* __restrict__ vl_,
    f16* __restrict__ oh_, f16* __restrict__ ol_) {
  __shared__ float S[32][548];
  const int bh = blockIdx.y;
  const int m0 = blockIdx.x * 32;
  const int tid = threadIdx.x, lane = tid & 63, wv = tid >> 6;
  const int lr = lane & 15, lgp = lane >> 4;

  // Q fragments (held in registers)
  f16x8 qh[2][4], ql[2][4];
  {
    const size_t qbase = ((size_t)bh * 512 + m0) * 128;
#pragma unroll
    for (int mt = 0; mt < 2; mt++)
#pragma unroll
      for (int kb = 0; kb < 4; kb++) {
        size_t off = qbase + (size_t)(mt * 16 + lr) * 128 + kb * 32 + lgp * 8;
        qh[mt][kb] = *(const f16x8*)&qh_[off];
        ql[mt][kb] = *(const f16x8*)&ql_[off];
      }
  }

  // phase 1: content scores  S[m][j] = q[m] . k[m0+j]
  {
    const size_t kbase = ((size_t)bh * 1024 + m0) * 128;
    int ntB = (wv < 2) ? wv * 9 : 18 + (wv - 2) * 8;
    int ntE = ntB + ((wv < 2) ? 9 : 8);
    for (int nt = ntB; nt < ntE; ++nt) {
      f16x8 kh[4], kl[4];
#pragma unroll
      for (int kb = 0; kb < 4; kb++) {
        size_t off = kbase + (size_t)(nt * 16 + lr) * 128 + kb * 32 + lgp * 8;
        kh[kb] = *(const f16x8*)&kh_[off];
        kl[kb] = *(const f16x8*)&kl_[off];
      }
      f32x4 aM[2], aC[2];
      aM[0] = zero4(); aM[1] = zero4(); aC[0] = zero4(); aC[1] = zero4();
#pragma unroll
      for (int kb = 0; kb < 4; kb++)
#pragma unroll
        for (int mt = 0; mt < 2; mt++) {
          aM[mt] = MFMA16(qh[mt][kb], kh[kb], aM[mt]);
          aC[mt] = MFMA16(qh[mt][kb], kl[kb], aC[mt]);
          aC[mt] = MFMA16(ql[mt][kb], kh[kb], aC[mt]);
        }
#pragma unroll
      for (int mt = 0; mt < 2; mt++)
#pragma unroll
        for (int rg = 0; rg < 4; rg++) {
          int m = mt * 16 + lgp * 4 + rg;
          S[m][nt * 16 + lr] = aM[mt][rg] + aC[mt][rg] * LO_INV;
        }
    }
  }
  __syncthreads();

  // phase 2: positional scores  S[m][m+l] += q[m] . pe[l]
  {
    for (int lt = wv * 8; lt < wv * 8 + 8; ++lt) {
      f16x8 eh[4], el[4];
#pragma unroll
      for (int kb = 0; kb < 4; kb++) {
        size_t off = (size_t)(lt * 16 + lr) * 128 + kb * 32 + lgp * 8;
        eh[kb] = *(const f16x8*)&ph_[off];
        el[kb] = *(const f16x8*)&pl_[off];
      }
      f32x4 aM[2], aC[2];
      aM[0] = zero4(); aM[1] = zero4(); aC[0] = zero4(); aC[1] = zero4();
#pragma unroll
      for (int kb = 0; kb < 4; kb++)
#pragma unroll
        for (int mt = 0; mt < 2; mt++) {
          aM[mt] = MFMA16(qh[mt][kb], eh[kb], aM[mt]);
          aC[mt] = MFMA16(qh[mt][kb], el[kb], aC[mt]);
          aC[mt] = MFMA16(ql[mt][kb], eh[kb], aC[mt]);
        }
#pragma unroll
      for (int mt = 0; mt < 2; mt++)
#pragma unroll
        for (int rg = 0; rg < 4; rg++) {
          int m = mt * 16 + lgp * 4 + rg;
          int lc = lt * 16 + lr;
          S[m][m + lc] += aM[mt][rg] + aC[mt][rg] * LO_INV;
        }
    }
  }
  __syncthreads();

  // phase 3: softmax over each row's valid window [m, m+512), write packed split P
  {
    const float scl = 0.08838834764831843f;  // 1/sqrt(128)
    for (int rr = 0; rr < 8; ++rr) {
      int m = wv * 8 + rr;
      float mx = -3.0e38f;
#pragma unroll
      for (int it = 0; it < 9; ++it) {
        int j = it * 64 + lane;
        if (j < 544 && j >= m && j < m + 512) mx = fmaxf(mx, S[m][j]);
      }
#pragma unroll
      for (int o = 32; o > 0; o >>= 1) mx = fmaxf(mx, __shfl_xor(mx, o));
      float pv[9]; float sm = 0.f;
#pragma unroll
      for (int it = 0; it < 9; ++it) {
        int j = it * 64 + lane;
        float p = 0.f;
        if (j < 544 && j >= m && j < m + 512) p = expf((S[m][j] - mx) * scl);
        pv[it] = p; sm += p;
      }
#pragma unroll
      for (int o = 32; o > 0; o >>= 1) sm += __shfl_xor(sm, o);
      float inv = 1.0f / sm;
#pragma unroll
      for (int it = 0; it < 9; ++it) {
        int j = it * 64 + lane;
        if (j < 544) {
          float pn = pv[it] * inv;
          f16 hh, ll; split2(pn, &hh, &ll);
          unsigned pk = (unsigned)__builtin_bit_cast(unsigned short, hh) |
                        ((unsigned)__builtin_bit_cast(unsigned short, ll) << 16);
          ((unsigned*)&S[m][0])[j] = pk;
        }
      }
    }
  }
  __syncthreads();

  // phase 4: O[m][d] = sum_j P[m][j] * V[m0+j][d]   (V stored transposed [d][pos])
  f32x4 accM[2][2], accC[2][2];
#pragma unroll
  for (int i = 0; i < 2; i++)
#pragma unroll
    for (int j = 0; j < 2; j++) { accM[i][j] = zero4(); accC[i][j] = zero4(); }
  for (int kb = 0; kb < 17; ++kb) {
    f16x8 pah[2], pal[2];
#pragma unroll
    for (int mt = 0; mt < 2; mt++) {
      const unsigned* sp = (const unsigned*)&S[mt * 16 + lr][0] + kb * 32 + lgp * 8;
      unpack_p(sp, &pah[mt], &pal[mt]);
    }
#pragma unroll
    for (int ntl = 0; ntl < 2; ++ntl) {
      int d = wv * 32 + ntl * 16 + lr;
      size_t off = ((size_t)bh * 128 + d) * 1024 + m0 + kb * 32 + lgp * 8;
      f16x8 vh = *(const f16x8*)&vh_[off];
      f16x8 vl = *(const f16x8*)&vl_[off];
#pragma unroll
      for (int mt = 0; mt < 2; mt++) {
        accM[mt][ntl] = MFMA16(pah[mt], vh, accM[mt][ntl]);
        accC[mt][ntl] = MFMA16(pah[mt], vl, accC[mt][ntl]);
        accC[mt][ntl] = MFMA16(pal[mt], vh, accC[mt][ntl]);
      }
    }
  }
  const int b = bh >> 3, hd = bh & 7;
#pragma unroll
  for (int mt = 0; mt < 2; mt++)
#pragma unroll
    for (int ntl = 0; ntl < 2; ntl++)
#pragma unroll
      for (int rg = 0; rg < 4; rg++) {
        int m = mt * 16 + lgp * 4 + rg;
        int d = wv * 32 + ntl * 16 + lr;
        float v = accM[mt][ntl][rg] + accC[mt][ntl][rg] * LO_INV;
        size_t ad = ((size_t)(b * 512 + m0 + m)) * 1024 + hd * 128 + d;
        f16 hh, ll; split2(v, &hh, &ll);
        oh_[ad] = hh; ol_[ad] = ll;
      }
}

// ---------------------------------------------------------------------------
// LayerNorm helpers / kernels (fp32)
// ---------------------------------------------------------------------------
__device__ __forceinline__ float blk_sum(float v, float* red) {
#pragma unroll
  for (int o = 32; o > 0; o >>= 1) v += __shfl_xor(v, o);
  int wv = threadIdx.x >> 6;
  if ((threadIdx.x & 63) == 0) red[wv] = v;
  __syncthreads();
  float r = red[0] + red[1] + red[2] + red[3];
  __syncthreads();
  return r;
}

__global__ void __launch_bounds__(256) ln1_k(const float* __restrict__ h,
                                             const float* __restrict__ ap,
                                             const float* __restrict__ g,
                                             const float* __restrict__ bb,
                                             float* __restrict__ h1,
                                             f16* __restrict__ h1h) {
  int row = blockIdx.x;
  __shared__ float red[4];
  float4 hv = ((const float4*)(h + (size_t)row * 1024))[threadIdx.x];
  float4 av = ((const float4*)(ap + (size_t)row * 1024))[threadIdx.x];
  float4 x; x.x = hv.x + av.x; x.y = hv.y + av.y; x.z = hv.z + av.z; x.w = hv.w + av.w;
  float s = x.x + x.y + x.z + x.w;
  s = blk_sum(s, red);
  float mean = s * (1.0f / 1024.0f);
  float4 d; d.x = x.x - mean; d.y = x.y - mean; d.z = x.z - mean; d.w = x.w - mean;
  float s2 = d.x * d.x + d.y * d.y + d.z * d.z + d.w * d.w;
  s2 = blk_sum(s2, red);
  float var = s2 * (1.0f / 1024.0f);
  float inv = 1.0f / sqrtf(var + 1e-5f);
  float4 gv = ((const float4*)g)[threadIdx.x];
  float4 bv = ((const float4*)bb)[threadIdx.x];
  float4 y; y.x = d.x * inv * gv.x + bv.x; y.y = d.y * inv * gv.y + bv.y;
  y.z = d.z * inv * gv.z + bv.z; y.w = d.w * inv * gv.w + bv.w;
  ((float4*)(h1 + (size_t)row * 1024))[threadIdx.x] = y;
  f16x4 yh; yh[0] = (f16)y.x; yh[1] = (f16)y.y; yh[2] = (f16)y.z; yh[3] = (f16)y.w;
  *(f16x4*)&h1h[(size_t)row * 1024 + threadIdx.x * 4] = yh;
}

// ---------------------------------------------------------------------------
// Gate: logits = h1 @ gate_W + gate_b, top-2, softmax, counts
// ---------------------------------------------------------------------------
__global__ void __launch_bounds__(256) gate_k(const float* __restrict__ h1,
                                              const float* __restrict__ gW,
                                              const float* __restrict__ gb,
                                              float* __restrict__ outIdx,
                                              float* __restrict__ sc,
                                              int* __restrict__ te,
                                              int* __restrict__ ctrl) {
  int t = blockIdx.x * 4 + (threadIdx.x >> 6);
  int lane = threadIdx.x & 63;
  float a0 = 0, a1 = 0, a2 = 0, a3 = 0, a4 = 0, a5 = 0, a6 = 0, a7 = 0;
  for (int i = lane; i < 1024; i += 64) {
    float x = h1[(size_t)t * 1024 + i];
    const float4* w = (const float4*)&gW[i * 8];
    float4 w0 = w[0], w1 = w[1];
    a0 += x * w0.x; a1 += x * w0.y; a2 += x * w0.z; a3 += x * w0.w;
    a4 += x * w1.x; a5 += x * w1.y; a6 += x * w1.z; a7 += x * w1.w;
  }
  float av[8] = {a0, a1, a2, a3, a4, a5, a6, a7};
#pragma unroll
  for (int e = 0; e < 8; e++)
#pragma unroll
    for (int o = 32; o > 0; o >>= 1) av[e] += __shfl_xor(av[e], o);
  if (lane == 0) {
#pragma unroll
    for (int e = 0; e < 8; e++) av[e] += gb[e];
    int i0 = 0; float v0 = av[0];
#pragma unroll
    for (int e = 1; e < 8; e++) if (av[e] > v0) { v0 = av[e]; i0 = e; }
    int i1 = -1; float v1 = -3.0e38f;
#pragma unroll
    for (int e = 0; e < 8; e++) if (e != i0 && av[e] > v1) { v1 = av[e]; i1 = e; }
    float ex = expf(v1 - v0);
    float den = 1.0f + ex;
    outIdx[t * 2] = (float)i0; outIdx[t * 2 + 1] = (float)i1;
    sc[t * 2] = 1.0f / den; sc[t * 2 + 1] = ex / den;
    te[t * 2] = i0; te[t * 2 + 1] = i1;
    atomicAdd(&ctrl[i0], 1); atomicAdd(&ctrl[i1], 1);
  }
}

__global__ void scan_k(int* ctrl) {
  if (threadIdx.x == 0 && blockIdx.x == 0) {
    int s = 0;
    for (int e = 0; e < 8; e++) { ctrl[8 + e] = s; s += ctrl[e]; }
  }
}

__global__ void __launch_bounds__(256) scatter_k(const int* __restrict__ te,
                                                 int* ctrl,
                                                 int* __restrict__ list,
                                                 int* __restrict__ ppos) {
  int t = blockIdx.x * 256 + threadIdx.x;
  if (t >= 2048) return;
#pragma unroll
  for (int s = 0; s < 2; s++) {
    int e = te[t * 2 + s];
    int pos = atomicAdd(&ctrl[16 + e], 1);
    int pr = ctrl[8 + e] + pos;
    list[pr] = t;
    ppos[t * 2 + s] = pr;
  }
}

// ---------------------------------------------------------------------------
// Combine MoE outputs + final LayerNorm
// ---------------------------------------------------------------------------
__global__ void __launch_bounds__(256) comb_ln2_k(const float* __restrict__ h1,
                                                  const float* __restrict__ ye,
                                                  const float* __restrict__ sc,
                                                  const int* __restrict__ ppos,
                                                  const float* __restrict__ g,
                                                  const float* __restrict__ bb,
                                                  float* __restrict__ out) {
  int row = blockIdx.x;
  __shared__ float red[4];
  int p0 = ppos[row * 2], p1 = ppos[row * 2 + 1];
  float s0 = sc[row * 2], s1 = sc[row * 2 + 1];
  float4 a = ((const float4*)(h1 + (size_t)row * 1024))[threadIdx.x];
  float4 y0 = ((const float4*)(ye + (size_t)p0 * 1024))[threadIdx.x];
  float4 y1 = ((const float4*)(ye + (size_t)p1 * 1024))[threadIdx.x];
  float4 x;
  x.x = a.x + s0 * y0.x + s1 * y1.x; x.y = a.y + s0 * y0.y + s1 * y1.y;
  x.z = a.z + s0 * y0.z + s1 * y1.z; x.w = a.w + s0 * y0.w + s1 * y1.w;
  float s = x.x + x.y + x.z + x.w;
  s = blk_sum(s, red);
  float mean = s * (1.0f / 1024.0f);
  float4 d; d.x = x.x - mean; d.y = x.y - mean; d.z = x.z - mean; d.w = x.w - mean;
  float s2 = d.x * d.x + d.y * d.y + d.z * d.z + d.w * d.w;
  s2 = blk_sum(s2, red);
  float var = s2 * (1.0f / 1024.0f);
  float inv = 1.0f / sqrtf(var + 1e-5f);
  float4 gv = ((const float4*)g)[threadIdx.x];
  float4 bv = ((const float4*)bb)[threadIdx.x];
  float4 y; y.x = d.x * inv * gv.x + bv.x; y.y = d.y * inv * gv.y + bv.y;
  y.z = d.z * inv * gv.z + bv.z; y.w = d.w * inv * gv.w + bv.w;
  ((float4*)(out + (size_t)row * 1024))[threadIdx.x] = y;
}

// ---------------------------------------------------------------------------
// Host launch
// ---------------------------------------------------------------------------
extern "C" void kernel_launch(void* const* d_in, const int* in_sizes, int n_in,
                              void* d_out, int out_size, void* d_ws, size_t ws_size,
                              hipStream_t stream) {
  const float* h   = (const float*)d_in[0];
  const float* hc  = (const float*)d_in[1];
  const float* pe  = (const float*)d_in[2];
  const float* Wq  = (const float*)d_in[3];
  const float* Wk  = (const float*)d_in[4];
  const float* Wv  = (const float*)d_in[5];
  const float* Wo  = (const float*)d_in[6];
  const float* g1  = (const float*)d_in[7];
  const float* b1n = (const float*)d_in[8];
  const float* gW  = (const float*)d_in[9];
  const float* gb  = (const float*)d_in[10];
  const float* W1  = (const float*)d_in[11];
  const float* b1e = (const float*)d_in[12];
  const float* W2  = (const float*)d_in[13];
  const float* b2e = (const float*)d_in[14];
  const float* g2  = (const float*)d_in[15];
  const float* b2n = (const float*)d_in[16];
  float* out = (float*)d_out;
  float* outIdx = out + 2097152;

  char* w = (char*)d_ws;
  size_t off = 0;
  auto alloc = [&](size_t bytes) -> char* {
    char* p = w + off;
    off += (bytes + 255) & ~(size_t)255;
    return p;
  };
  int*   ctrl    = (int*)alloc(128);
  f16*   hallH   = (f16*)alloc(4096ull * 1024 * 2);
  f16*   hallL   = (f16*)alloc(4096ull * 1024 * 2);
  f16*   WqkvtH  = (f16*)alloc(3072ull * 1024 * 2);   // frag-major
  f16*   WqkvtL  = (f16*)alloc(3072ull * 1024 * 2);
  f16*   WotH    = (f16*)alloc(1024ull * 1024 * 2);   // frag-major
  f16*   WotL    = (f16*)alloc(1024ull * 1024 * 2);
  f16*   peH     = (f16*)alloc(512ull * 128 * 2);
  f16*   peL     = (f16*)alloc(512ull * 128 * 2);
  // contiguous qkv block; offsets hard-coded in EP_QKV epilogue
  f16*   qkv     = (f16*)alloc(20971520ull * 2);
  f16*   qH  = qkv;
  f16*   qL  = qH + (1u << 21);
  f16*   kH  = qL + (1u << 21);
  f16*   kL  = kH + (1u << 22);
  f16*   vtH = kL + (1u << 22);
  f16*   vtL = vtH + (1u << 22);
  f16*   attH  = (f16*)alloc(2097152ull * 2);
  f16*   attL  = (f16*)alloc(2097152ull * 2);
  float* aproj = (float*)alloc(2097152ull * 4);
  float* h1    = (float*)alloc(2097152ull * 4);
  f16*   h1h   = (f16*)alloc(2097152ull * 2);
  f16*   W1t   = (f16*)alloc(16777216ull * 2);        // frag-major per expert
  f16*   W2t   = (f16*)alloc(16777216ull * 2);
  f16*   he    = (f16*)alloc(4224ull * 2048 * 2);
  float* ye    = (float*)alloc(4224ull * 1024 * 4);
  float* scb   = (float*)alloc(2048ull * 2 * 4);
  int*   te    = (int*)alloc(2048ull * 2 * 4);
  int*   ppos  = (int*)alloc(2048ull * 2 * 4);
  int*   list  = (int*)alloc(4096ull * 4);
  (void)in_sizes; (void)n_in; (void)out_size; (void)ws_size;

  hipMemsetAsync(ctrl, 0, 128, stream);

  // casts / weight prep (frag-major)
  cast_hall_k<<<2048, 256, 0, stream>>>(h, hc, hallH, hallL);
  wprep_k<1><<<dim3(32, 32, 1), 256, 0, stream>>>(Wq, WqkvtH, WqkvtL, 1024, 1024);
  wprep_k<1><<<dim3(32, 32, 1), 256, 0, stream>>>(Wk, WqkvtH + 1048576, WqkvtL + 1048576, 1024, 1024);
  wprep_k<1><<<dim3(32, 32, 1), 256, 0, stream>>>(Wv, WqkvtH + 2097152, WqkvtL + 2097152, 1024, 1024);
  wprep_k<1><<<dim3(32, 32, 1), 256, 0, stream>>>(Wo, WotH, WotL, 1024, 1024);
  transpose_cast_k<1><<<dim3(16, 4, 1), 256, 0, stream>>>(pe, peH, peL, 128, 512);
  wprep_k<0><<<dim3(64, 32, 8), 256, 0, stream>>>(W1, W1t, nullptr, 1024, 2048);
  wprep_k<0><<<dim3(32, 64, 8), 256, 0, stream>>>(W2, W2t, nullptr, 2048, 1024);

  // merged QKV projection over h_all (N=3072): 1536 blocks, 128x64 split tile
  gemm_k<1, 128, 64, AM_ID, EP_QKV><<<dim3(48, 32, 1), 256, 0, stream>>>(
      hallH, hallL, WqkvtH, WqkvtL, qkv, nullptr, nullptr, 1024, 1024, 0,
      nullptr, nullptr, nullptr);

  // attention
  attn_k<<<dim3(16, 32, 1), 256, 0, stream>>>(qH, qL, kH, kL, peH, peL, vtH, vtL, attH, attL);

  // output projection + LN1 (64x64 tile: 512 blocks)
  gemm_k<1, 64, 64, AM_ID, EP_F32><<<dim3(16, 32, 1), 256, 0, stream>>>(
      attH, attL, WotH, WotL, aproj, nullptr, nullptr, 1024, 1024, 0,
      nullptr, nullptr, nullptr);
  ln1_k<<<2048, 256, 0, stream>>>(h, aproj, g1, b1n, h1, h1h);

  // gate + routing
  gate_k<<<512, 256, 0, stream>>>(h1, gW, gb, outIdx, scb, te, ctrl);
  scan_k<<<1, 64, 0, stream>>>(ctrl);
  scatter_k<<<8, 256, 0, stream>>>(te, ctrl, list, ppos);

  // expert FFNs (64-row tiles)
  gemm_k<0, 64, 128, AM_GA, EP_HE><<<dim3(16, 32, 8), 256, 0, stream>>>(
      h1h, nullptr, W1t, nullptr, he, nullptr, b1e, 1024, 1024, 2048 * 1024,
      list, ctrl + 8, ctrl);
  gemm_k<0, 64, 128, AM_PA, EP_YE><<<dim3(8, 32, 8), 256, 0, stream>>>(
      he, nullptr, W2t, nullptr, ye, nullptr, b2e, 2048, 2048, 1024 * 2048,
      nullptr, ctrl + 8, ctrl);

  // combine + LN2
  comb_ln2_k<<<2048, 256, 0, stream>>>(h1, ye, scb, ppos, g2, b2n, out);
}